// Round 5
// baseline (125.852 us; speedup 1.0000x reference)
//
#include <hip/hip_runtime.h>
#include <hip/hip_bf16.h>

#define H1 57   // 64-8+1
#define H2 53   // 57-5+1
#define XP 60   // padded x-stride of conv1 output (f16x4 units)

typedef _Float16 f16;
typedef _Float16 f16x4 __attribute__((ext_vector_type(4)));
typedef _Float16 f16x8 __attribute__((ext_vector_type(8)));
typedef float f32x4 __attribute__((ext_vector_type(4)));

// ---------------- weight repack (unchanged from round 4) ----------------
__global__ __launch_bounds__(256) void k_repack(const float* __restrict__ w1,
    const float* __restrict__ w2, f16* __restrict__ w1f, f16* __restrict__ w2f)
{
  int t = threadIdx.x;
  for (int i = t; i < 8 * 64 * 8; i += 256) {
    int j = i & 7;
    int l = (i >> 3) & 63;
    int tp = i >> 9;
    int c = j & 3;
    int kh = tp;
    int kw = 4 * (j >> 2) + (l >> 4);
    int oc = l & 15;
    float v = (c < 3) ? w1[((oc * 3 + c) * 8 + kh) * 8 + kw] : 0.f;
    w1f[i] = (f16)v;
  }
  for (int i = t; i < 13 * 2 * 64 * 8; i += 256) {
    int j = i & 7;
    int l = (i >> 3) & 63;
    int h = (i >> 9) & 1;
    int tp = i >> 10;
    int tap = 2 * tp + (j >> 2);
    int c = ((l >> 4) << 2) + (j & 3);
    int oc = (l & 15) + (h << 4);
    float v = (tap < 25) ? w2[((oc * 16 + c) * 5 + tap / 5) * 5 + tap % 5] : 0.f;
    w2f[i] = (f16)v;
  }
}

// ---------------- conv1 via MFMA implicit GEMM ----------------
// grid (512, 8): y0 = min(8*by, 49). block 256 = 4 waves.
// Hoisted LDS base pointers + const offsets -> ds_read2_b64 per MFMA.
__global__ __launch_bounds__(256) void k_conv1(const float* __restrict__ in,
    const f16* __restrict__ w1f, const float* __restrict__ b1,
    f16* __restrict__ O1)
{
  __shared__ __align__(16) f16 sIn[15][72][4];   // 8640 B, c4 channels-last
  __shared__ __align__(16) f16 sW[8 * 64 * 8];   // 8192 B
  __shared__ __align__(16) f16 sT[4][64][20];    // 10240 B, per-wave transpose
  const int img = blockIdx.x;
  const int y0 = min((int)blockIdx.y * 8, 49);
  for (int i = threadIdx.x; i < 512; i += 256)
    ((float4*)sW)[i] = ((const float4*)w1f)[i];
  for (int i = threadIdx.x; i < 15 * 16; i += 256) {
    int y = i >> 4, xq = i & 15;
    const float* p0 = &in[(((size_t)img * 3 + 0) * 64 + (y0 + y)) * 64 + xq * 4];
    float4 v0 = *(const float4*)p0;
    float4 v1 = *(const float4*)(p0 + 4096);
    float4 v2 = *(const float4*)(p0 + 8192);
    float c0[4] = {v0.x, v0.y, v0.z, v0.w};
    float c1[4] = {v1.x, v1.y, v1.z, v1.w};
    float c2[4] = {v2.x, v2.y, v2.z, v2.w};
    #pragma unroll
    for (int q = 0; q < 4; ++q) {
      f16x4 tt = {(f16)c0[q], (f16)c1[q], (f16)c2[q], (f16)0.f};
      *(f16x4*)&sIn[y][xq * 4 + q][0] = tt;
    }
  }
  for (int i = threadIdx.x; i < 15 * 8; i += 256) {
    int y = i >> 3, xi = i & 7;
    *(f16x4*)&sIn[y][64 + xi][0] = (f16x4){(f16)0.f, (f16)0.f, (f16)0.f, (f16)0.f};
  }
  __syncthreads();

  const int lane = threadIdx.x & 63;
  const int wv = threadIdx.x >> 6;
  const int g = lane >> 4;       // k-group (A) / D-row group
  const int n16 = lane & 15;     // A row (pixel) / D col (oc)

  f16x8 Bf[8];
  #pragma unroll
  for (int tp = 0; tp < 8; ++tp)
    Bf[tp] = *(const f16x8*)&sW[(tp * 64 + lane) * 8];

  const float bias = b1[n16];
  f32x4 acc[2][4];
  #pragma unroll
  for (int r = 0; r < 2; ++r)
    #pragma unroll
    for (int xt = 0; xt < 4; ++xt)
      acc[r][xt] = (f32x4){bias, bias, bias, bias};

  // hoisted per-(r,xt) LDS bases; tp advances by a constant 288 f16
  const f16* pA[2][4];
  #pragma unroll
  for (int r = 0; r < 2; ++r)
    #pragma unroll
    for (int xt = 0; xt < 4; ++xt)
      pA[r][xt] = &sIn[2 * wv + r][xt * 16 + n16 + g][0];

  #pragma unroll
  for (int tp = 0; tp < 8; ++tp) {        // kh = tp; base offset tp*288 f16
    #pragma unroll
    for (int r = 0; r < 2; ++r) {
      #pragma unroll
      for (int xt = 0; xt < 4; ++xt) {
        const f16* p = pA[r][xt] + tp * 288;
        f16x4 a0 = *(const f16x4*)(p);        // kw = g
        f16x4 a1 = *(const f16x4*)(p + 16);   // kw = 4+g
        union { struct { f16x4 lo, hi; } pr; f16x8 v; } u;
        u.pr.lo = a0; u.pr.hi = a1;
        acc[r][xt] = __builtin_amdgcn_mfma_f32_16x16x32_f16(u.v, Bf[tp], acc[r][xt], 0, 0, 0);
      }
    }
  }

  // epilogue: relu, per-wave LDS transpose (oc-major -> c4), coalesced store
  #pragma unroll
  for (int r = 0; r < 2; ++r) {
    #pragma unroll
    for (int xt = 0; xt < 4; ++xt)
      #pragma unroll
      for (int q = 0; q < 4; ++q)
        sT[wv][xt * 16 + g * 4 + q][n16] = (f16)fmaxf(acc[r][xt][q], 0.f);
    const int yy = y0 + 2 * wv + r;
    if (lane < H1) {
      #pragma unroll
      for (int go = 0; go < 4; ++go) {
        f16x4 v = *(const f16x4*)&sT[wv][lane][go * 4];
        *(f16x4*)&O1[(((size_t)(img * 4 + go) * H1 + yy) * XP + lane) * 4] = v;
      }
    }
  }
}

// ---------------- conv2 via MFMA implicit GEMM + fused global max ----------------
// grid (512, 7): y0 in {0,8,...,40,45}. block 256 = 4 waves.
// Hoisted bases + compile-time tap offsets -> ds_read2_b64 / ds_read_b128 imm.
__global__ __launch_bounds__(256) void k_conv2(const f16* __restrict__ O1,
    const f16* __restrict__ w2f, const float* __restrict__ b2,
    float* __restrict__ feat)
{
  __shared__ __align__(16) f16 sW[13 * 2 * 64 * 8];          // 26624 B
  __shared__ __align__(16) f16 sI[4 * 12 * XP * 4 + 64];     // 23168 B
  __shared__ unsigned smax[32];
  const int img = blockIdx.x;
  const int y0 = min((int)blockIdx.y * 8, 45);
  if (threadIdx.x < 32) smax[threadIdx.x] = 0u;
  for (int i = threadIdx.x; i < 1664; i += 256)
    ((float4*)sW)[i] = ((const float4*)w2f)[i];
  for (int i = threadIdx.x; i < 4 * 360; i += 256) {
    int gg = i / 360, r = i % 360;
    ((float4*)sI)[gg * 360 + r] =
        *(const float4*)(O1 + (((size_t)(img * 4 + gg) * H1 + y0) * XP) * 4 + r * 8);
  }
  __syncthreads();

  const int lane = threadIdx.x & 63;
  const int wv = threadIdx.x >> 6;
  const int g = lane >> 4;
  const int n16 = lane & 15;

  f32x4 acc[2][4][2];
  #pragma unroll
  for (int r = 0; r < 2; ++r)
    #pragma unroll
    for (int xt = 0; xt < 4; ++xt)
      #pragma unroll
      for (int h = 0; h < 2; ++h)
        acc[r][xt][h] = (f32x4){0.f, 0.f, 0.f, 0.f};

  // hoisted per-(r,xt) bases (g folds the k-group row block) and B base
  const f16* pA[2][4];
  #pragma unroll
  for (int r = 0; r < 2; ++r)
    #pragma unroll
    for (int xt = 0; xt < 4; ++xt)
      pA[r][xt] = &sI[((g * 12 + 2 * wv + r) * XP + xt * 16 + n16) * 4];
  const f16* pB = &sW[lane * 8];

  #pragma unroll
  for (int tp = 0; tp < 13; ++tp) {
    f16x8 B0 = *(const f16x8*)(pB + (tp * 2 + 0) * 512);
    f16x8 B1 = *(const f16x8*)(pB + (tp * 2 + 1) * 512);
    const int t0 = 2 * tp;
    const int t1 = (t0 + 1 < 25) ? t0 + 1 : 0;    // tap 25 is zero-weight
    const int O0 = ((t0 / 5) * XP + (t0 % 5)) * 4;  // const after unroll
    const int O1o = ((t1 / 5) * XP + (t1 % 5)) * 4;
    #pragma unroll
    for (int r = 0; r < 2; ++r) {
      #pragma unroll
      for (int xt = 0; xt < 4; ++xt) {
        f16x4 a0 = *(const f16x4*)(pA[r][xt] + O0);
        f16x4 a1 = *(const f16x4*)(pA[r][xt] + O1o);
        union { struct { f16x4 lo, hi; } pr; f16x8 v; } u;
        u.pr.lo = a0; u.pr.hi = a1;
        acc[r][xt][0] = __builtin_amdgcn_mfma_f32_16x16x32_f16(u.v, B0, acc[r][xt][0], 0, 0, 0);
        acc[r][xt][1] = __builtin_amdgcn_mfma_f32_16x16x32_f16(u.v, B1, acc[r][xt][1], 0, 0, 0);
      }
    }
  }

  const float bias0 = b2[n16];
  const float bias1 = b2[n16 + 16];
  float m0 = 0.f, m1 = 0.f;
  #pragma unroll
  for (int r = 0; r < 2; ++r)
    #pragma unroll
    for (int xt = 0; xt < 4; ++xt)
      #pragma unroll
      for (int q = 0; q < 4; ++q) {
        int px = xt * 16 + g * 4 + q;
        if (px < H2) {
          m0 = fmaxf(m0, acc[r][xt][0][q] + bias0);
          m1 = fmaxf(m1, acc[r][xt][1][q] + bias1);
        }
      }
  m0 = fmaxf(m0, 0.f);
  m1 = fmaxf(m1, 0.f);
  m0 = fmaxf(m0, __shfl_xor(m0, 16, 64));
  m0 = fmaxf(m0, __shfl_xor(m0, 32, 64));
  m1 = fmaxf(m1, __shfl_xor(m1, 16, 64));
  m1 = fmaxf(m1, __shfl_xor(m1, 32, 64));
  if (g == 0) {
    atomicMax(&smax[n16], __float_as_uint(m0));
    atomicMax(&smax[n16 + 16], __float_as_uint(m1));
  }
  __syncthreads();
  if (threadIdx.x < 32)
    atomicMax((unsigned*)&feat[img * 32 + threadIdx.x], smax[threadIdx.x]);
}

// ---------------- head: adjacency + graph layer + MLP ----------------
__global__ __launch_bounds__(256) void k_head(const float* __restrict__ diffs,
    const float* __restrict__ feat, const float* __restrict__ gw,
    const float* __restrict__ gb, const float* __restrict__ w4,
    const float* __restrict__ b4, const float* __restrict__ w5,
    const float* __restrict__ b5, float* __restrict__ out)
{
  __shared__ float h66[4][66];
  __shared__ float hout[4][512];
  __shared__ float Am[4][4];
  __shared__ float pd[4][4][2];
  __shared__ float fs[4][32];
  const int b = blockIdx.x;
  const int tid = threadIdx.x;
  if (tid < 128) {
    int i = tid >> 5, c = tid & 31;
    fs[i][c] = feat[(b * 4 + i) * 32 + c];
  }
  if (tid == 0) {
    float lx[4], ly[4];
    #pragma unroll
    for (int a = 0; a < 4; ++a) {
      lx[a] = diffs[(b * 4 + a) * 2];
      ly[a] = diffs[(b * 4 + a) * 2 + 1];
    }
    #pragma unroll
    for (int i = 0; i < 4; ++i) {
      float A[4];
      float rs = 0.f;
      #pragma unroll
      for (int j = 0; j < 4; ++j) {
        float dx = lx[i] - lx[j], dy = ly[i] - ly[j];
        pd[i][j][0] = dx;
        pd[i][j][1] = dy;
        float n = sqrtf(dx * dx + dy * dy);
        A[j] = (n < 1.41421356237309504880f) ? 1.f : 0.f;
        rs += A[j];
      }
      float inv = 1.f / fmaxf(rs, 1e-6f);
      #pragma unroll
      for (int j = 0; j < 4; ++j)
        Am[i][j] = (i == j) ? 0.f : A[j] * inv;
    }
  }
  __syncthreads();
  if (tid < 128) {
    int i = tid >> 5, c = tid & 31;
    h66[i][c] = fs[i][c];
    float s = 0.f;
    #pragma unroll
    for (int j = 0; j < 4; ++j) s += Am[i][j] * fs[j][c];
    h66[i][32 + c] = s;
  } else if (tid < 136) {
    int q = tid - 128;
    int i = q >> 1, d = q & 1;
    float s = 0.f;
    #pragma unroll
    for (int j = 0; j < 4; ++j) s += Am[i][j] * pd[i][j][d];
    h66[i][64 + d] = s;
  }
  __syncthreads();
  #pragma unroll
  for (int r = 0; r < 2; ++r) {
    int o = tid + 256 * r;
    const float* wrow = &gw[o * 66];
    float a0 = gb[o], a1 = a0, a2 = a0, a3 = a0;
    for (int c = 0; c < 66; ++c) {
      float wv = wrow[c];
      a0 = fmaf(h66[0][c], wv, a0);
      a1 = fmaf(h66[1][c], wv, a1);
      a2 = fmaf(h66[2][c], wv, a2);
      a3 = fmaf(h66[3][c], wv, a3);
    }
    hout[0][o] = fmaxf(a0, 0.f);
    hout[1][o] = fmaxf(a1, 0.f);
    hout[2][o] = fmaxf(a2, 0.f);
    hout[3][o] = fmaxf(a3, 0.f);
  }
  __syncthreads();
  if (tid < 192) {
    int gq = tid >> 4, l = tid & 15;
    int i = gq / 3, k = gq % 3;
    const float* wrow = (k < 2) ? &w4[k * 512] : w5;
    float s = 0.f;
    for (int o = l; o < 512; o += 16) s = fmaf(hout[i][o], wrow[o], s);
    #pragma unroll
    for (int d = 8; d >= 1; d >>= 1) s += __shfl_xor(s, d, 16);
    if (l == 0) {
      if (k < 2) out[(b * 4 + i) * 2 + k] = s + b4[k];
      else       out[1024 + b * 4 + i] = s + b5[0];
    }
  }
}

extern "C" void kernel_launch(void* const* d_in, const int* in_sizes, int n_in,
                              void* d_out, int out_size, void* d_ws, size_t ws_size,
                              hipStream_t stream) {
  const float* diffs  = (const float*)d_in[0];
  const float* states = (const float*)d_in[1];
  const float* w1 = (const float*)d_in[2];
  const float* b1 = (const float*)d_in[3];
  const float* w2 = (const float*)d_in[4];
  const float* b2 = (const float*)d_in[5];
  const float* gw = (const float*)d_in[6];
  const float* gb = (const float*)d_in[7];
  const float* w4 = (const float*)d_in[8];
  const float* b4 = (const float*)d_in[9];
  const float* w5 = (const float*)d_in[10];
  const float* b5 = (const float*)d_in[11];
  float* out = (float*)d_out;

  char* base = (char*)d_ws;
  f16*   w1f = (f16*)base;                    // 8192 B
  f16*   w2f = (f16*)(base + 8192);           // 26624 B -> 34816
  float* feat = (float*)(base + 34816);       // 65536 B -> 100352
  f16*   O1  = (f16*)(base + 100352);         // 512*4*57*60*4 f16 = 56.0 MB

  hipMemsetAsync(feat, 0, 512 * 32 * sizeof(float), stream);  // atomicMax identity
  k_repack<<<1, 256, 0, stream>>>(w1, w2, w1f, w2f);
  k_conv1<<<dim3(512, 8), 256, 0, stream>>>(states, w1f, b1, O1);
  k_conv2<<<dim3(512, 7), 256, 0, stream>>>(O1, w2f, b2, feat);
  k_head<<<128, 256, 0, stream>>>(diffs, feat, gw, gb, w4, b4, w5, b5, out);
}

// Round 6
// 125.544 us; speedup vs baseline: 1.0025x; 1.0025x over previous
//
#include <hip/hip_runtime.h>
#include <hip/hip_bf16.h>

#define H1 57   // 64-8+1
#define H2 53   // 57-5+1
#define XP 60   // padded x-stride of conv1 output (f16x4 units)

typedef _Float16 f16;
typedef _Float16 f16x4 __attribute__((ext_vector_type(4)));
typedef _Float16 f16x8 __attribute__((ext_vector_type(8)));
typedef float f32x4 __attribute__((ext_vector_type(4)));

// ---------------- weight repack (unchanged) ----------------
// w1f[(tp*64+l)*8+j] = W1[oc=l&15][c=j&3][kh=tp][kw=4*(j>>2)+(l>>4)]  (c==3 -> 0)
// w2f[((tp*2+h)*64+l)*8+j] = W2[oc=(l&15)+16h][c=((l>>4)<<2)+(j&3)][tap=2tp+(j>>2)] (tap 25 -> 0)
__global__ __launch_bounds__(256) void k_repack(const float* __restrict__ w1,
    const float* __restrict__ w2, f16* __restrict__ w1f, f16* __restrict__ w2f)
{
  int t = threadIdx.x;
  for (int i = t; i < 8 * 64 * 8; i += 256) {
    int j = i & 7;
    int l = (i >> 3) & 63;
    int tp = i >> 9;
    int c = j & 3;
    int kh = tp;
    int kw = 4 * (j >> 2) + (l >> 4);
    int oc = l & 15;
    float v = (c < 3) ? w1[((oc * 3 + c) * 8 + kh) * 8 + kw] : 0.f;
    w1f[i] = (f16)v;
  }
  for (int i = t; i < 13 * 2 * 64 * 8; i += 256) {
    int j = i & 7;
    int l = (i >> 3) & 63;
    int h = (i >> 9) & 1;
    int tp = i >> 10;
    int tap = 2 * tp + (j >> 2);
    int c = ((l >> 4) << 2) + (j & 3);
    int oc = (l & 15) + (h << 4);
    float v = (tap < 25) ? w2[((oc * 16 + c) * 5 + tap / 5) * 5 + tap % 5] : 0.f;
    w2f[i] = (f16)v;
  }
}

// ---------------- conv1 via MFMA implicit GEMM ----------------
// grid (512, 8): y0 = min(8*by, 49). block 256 = 4 waves.
// B-fragments loaded straight from global (L2-hot, per-lane order) — no sW LDS.
__global__ __launch_bounds__(256) void k_conv1(const float* __restrict__ in,
    const f16* __restrict__ w1f, const float* __restrict__ b1,
    f16* __restrict__ O1)
{
  __shared__ __align__(16) f16 sIn[15][72][4];   // 8640 B, c4 channels-last
  __shared__ __align__(16) f16 sT[4][64][20];    // 10240 B, per-wave transpose
  const int img = blockIdx.x;
  const int y0 = min((int)blockIdx.y * 8, 49);
  const int lane = threadIdx.x & 63;
  const int wv = threadIdx.x >> 6;

  // B-fragments from global (coalesced 16B/lane; 8 KB total, L1/L2-hot)
  f16x8 Bf[8];
  #pragma unroll
  for (int tp = 0; tp < 8; ++tp)
    Bf[tp] = *(const f16x8*)&w1f[(tp * 64 + lane) * 8];

  // stage input strip: 15 rows x 64 x, 3 ch fp32 -> f16 c4
  for (int i = threadIdx.x; i < 15 * 16; i += 256) {
    int y = i >> 4, xq = i & 15;
    const float* p0 = &in[(((size_t)img * 3 + 0) * 64 + (y0 + y)) * 64 + xq * 4];
    float4 v0 = *(const float4*)p0;
    float4 v1 = *(const float4*)(p0 + 4096);
    float4 v2 = *(const float4*)(p0 + 8192);
    float c0[4] = {v0.x, v0.y, v0.z, v0.w};
    float c1[4] = {v1.x, v1.y, v1.z, v1.w};
    float c2[4] = {v2.x, v2.y, v2.z, v2.w};
    #pragma unroll
    for (int q = 0; q < 4; ++q) {
      f16x4 tt = {(f16)c0[q], (f16)c1[q], (f16)c2[q], (f16)0.f};
      *(f16x4*)&sIn[y][xq * 4 + q][0] = tt;
    }
  }
  for (int i = threadIdx.x; i < 15 * 8; i += 256) {
    int y = i >> 3, xi = i & 7;
    *(f16x4*)&sIn[y][64 + xi][0] = (f16x4){(f16)0.f, (f16)0.f, (f16)0.f, (f16)0.f};
  }
  __syncthreads();

  const int g = lane >> 4;       // k-group (A) / D-row group
  const int n16 = lane & 15;     // A row (pixel) / D col (oc)

  const float bias = b1[n16];
  f32x4 acc[2][4];
  #pragma unroll
  for (int r = 0; r < 2; ++r)
    #pragma unroll
    for (int xt = 0; xt < 4; ++xt)
      acc[r][xt] = (f32x4){bias, bias, bias, bias};

  #pragma unroll
  for (int tp = 0; tp < 8; ++tp) {        // kh = tp
    #pragma unroll
    for (int r = 0; r < 2; ++r) {
      const int row = 2 * wv + r + tp;
      #pragma unroll
      for (int xt = 0; xt < 4; ++xt) {
        const int px = xt * 16 + n16;
        f16x4 a0 = *(const f16x4*)&sIn[row][px + g][0];       // kw = g
        f16x4 a1 = *(const f16x4*)&sIn[row][px + 4 + g][0];   // kw = 4+g
        union { struct { f16x4 lo, hi; } pr; f16x8 v; } u;
        u.pr.lo = a0; u.pr.hi = a1;
        acc[r][xt] = __builtin_amdgcn_mfma_f32_16x16x32_f16(u.v, Bf[tp], acc[r][xt], 0, 0, 0);
      }
    }
  }

  // epilogue: relu, per-wave LDS transpose (oc-major -> c4), coalesced store
  #pragma unroll
  for (int r = 0; r < 2; ++r) {
    #pragma unroll
    for (int xt = 0; xt < 4; ++xt)
      #pragma unroll
      for (int q = 0; q < 4; ++q)
        sT[wv][xt * 16 + g * 4 + q][n16] = (f16)fmaxf(acc[r][xt][q], 0.f);
    const int yy = y0 + 2 * wv + r;
    if (lane < H1) {
      #pragma unroll
      for (int go = 0; go < 4; ++go) {
        f16x4 v = *(const f16x4*)&sT[wv][lane][go * 4];
        *(f16x4*)&O1[(((size_t)(img * 4 + go) * H1 + yy) * XP + lane) * 4] = v;
      }
    }
  }
}

// ---------------- conv2 via MFMA implicit GEMM + fused global max ----------------
// grid (512, 7): y0 in {0,8,...,40,45}. block 256 = 4 waves.
// B from global (software-pipelined 1 tp ahead); A addressing = round-4 form.
__global__ __launch_bounds__(256) void k_conv2(const f16* __restrict__ O1,
    const f16* __restrict__ w2f, const float* __restrict__ b2,
    float* __restrict__ feat)
{
  __shared__ __align__(16) f16 sI[4 * 12 * XP * 4 + 64];     // 23168 B
  __shared__ unsigned smax[32];
  const int img = blockIdx.x;
  const int y0 = min((int)blockIdx.y * 8, 45);
  if (threadIdx.x < 32) smax[threadIdx.x] = 0u;
  for (int i = threadIdx.x; i < 4 * 360; i += 256) {
    int gg = i / 360, r = i % 360;
    ((float4*)sI)[gg * 360 + r] =
        *(const float4*)(O1 + (((size_t)(img * 4 + gg) * H1 + y0) * XP) * 4 + r * 8);
  }
  __syncthreads();

  const int lane = threadIdx.x & 63;
  const int wv = threadIdx.x >> 6;
  const int g = lane >> 4;
  const int n16 = lane & 15;

  f32x4 acc[2][4][2];
  #pragma unroll
  for (int r = 0; r < 2; ++r)
    #pragma unroll
    for (int xt = 0; xt < 4; ++xt)
      #pragma unroll
      for (int h = 0; h < 2; ++h)
        acc[r][xt][h] = (f32x4){0.f, 0.f, 0.f, 0.f};

  const f16* pB = &w2f[lane * 8];
  f16x8 B0 = *(const f16x8*)(pB);
  f16x8 B1 = *(const f16x8*)(pB + 512);

  for (int tp = 0; tp < 13; ++tp) {
    f16x8 nB0, nB1;
    if (tp < 12) {
      nB0 = *(const f16x8*)(pB + (tp * 2 + 2) * 512);
      nB1 = *(const f16x8*)(pB + (tp * 2 + 3) * 512);
    }
    const int t0 = 2 * tp;
    const int t1c = (t0 + 1 < 25) ? t0 + 1 : 0;   // tap 25 is zero-weight; clamp addr
    const int kh0 = t0 / 5, kw0 = t0 % 5;
    const int kh1 = t1c / 5, kw1 = t1c % 5;
    #pragma unroll
    for (int r = 0; r < 2; ++r) {
      const int yl = 2 * wv + r;
      const int row0 = (g * 12 + yl + kh0) * XP;
      const int row1 = (g * 12 + yl + kh1) * XP;
      #pragma unroll
      for (int xt = 0; xt < 4; ++xt) {
        const int px = xt * 16 + n16;
        f16x4 a0 = *(const f16x4*)&sI[(row0 + px + kw0) * 4];
        f16x4 a1 = *(const f16x4*)&sI[(row1 + px + kw1) * 4];
        union { struct { f16x4 lo, hi; } pr; f16x8 v; } u;
        u.pr.lo = a0; u.pr.hi = a1;
        acc[r][xt][0] = __builtin_amdgcn_mfma_f32_16x16x32_f16(u.v, B0, acc[r][xt][0], 0, 0, 0);
        acc[r][xt][1] = __builtin_amdgcn_mfma_f32_16x16x32_f16(u.v, B1, acc[r][xt][1], 0, 0, 0);
      }
    }
    B0 = nB0;
    B1 = nB1;
  }

  const float bias0 = b2[n16];
  const float bias1 = b2[n16 + 16];
  float m0 = 0.f, m1 = 0.f;
  #pragma unroll
  for (int r = 0; r < 2; ++r)
    #pragma unroll
    for (int xt = 0; xt < 4; ++xt)
      #pragma unroll
      for (int q = 0; q < 4; ++q) {
        int px = xt * 16 + g * 4 + q;
        if (px < H2) {
          m0 = fmaxf(m0, acc[r][xt][0][q] + bias0);
          m1 = fmaxf(m1, acc[r][xt][1][q] + bias1);
        }
      }
  m0 = fmaxf(m0, 0.f);
  m1 = fmaxf(m1, 0.f);
  m0 = fmaxf(m0, __shfl_xor(m0, 16, 64));
  m0 = fmaxf(m0, __shfl_xor(m0, 32, 64));
  m1 = fmaxf(m1, __shfl_xor(m1, 16, 64));
  m1 = fmaxf(m1, __shfl_xor(m1, 32, 64));
  if (g == 0) {
    atomicMax(&smax[n16], __float_as_uint(m0));
    atomicMax(&smax[n16 + 16], __float_as_uint(m1));
  }
  __syncthreads();
  if (threadIdx.x < 32)
    atomicMax((unsigned*)&feat[img * 32 + threadIdx.x], smax[threadIdx.x]);
}

// ---------------- head: adjacency + graph layer + MLP ----------------
__global__ __launch_bounds__(256) void k_head(const float* __restrict__ diffs,
    const float* __restrict__ feat, const float* __restrict__ gw,
    const float* __restrict__ gb, const float* __restrict__ w4,
    const float* __restrict__ b4, const float* __restrict__ w5,
    const float* __restrict__ b5, float* __restrict__ out)
{
  __shared__ float h66[4][66];
  __shared__ float hout[4][512];
  __shared__ float Am[4][4];
  __shared__ float pd[4][4][2];
  __shared__ float fs[4][32];
  const int b = blockIdx.x;
  const int tid = threadIdx.x;
  if (tid < 128) {
    int i = tid >> 5, c = tid & 31;
    fs[i][c] = feat[(b * 4 + i) * 32 + c];
  }
  if (tid == 0) {
    float lx[4], ly[4];
    #pragma unroll
    for (int a = 0; a < 4; ++a) {
      lx[a] = diffs[(b * 4 + a) * 2];
      ly[a] = diffs[(b * 4 + a) * 2 + 1];
    }
    #pragma unroll
    for (int i = 0; i < 4; ++i) {
      float A[4];
      float rs = 0.f;
      #pragma unroll
      for (int j = 0; j < 4; ++j) {
        float dx = lx[i] - lx[j], dy = ly[i] - ly[j];
        pd[i][j][0] = dx;
        pd[i][j][1] = dy;
        float n = sqrtf(dx * dx + dy * dy);
        A[j] = (n < 1.41421356237309504880f) ? 1.f : 0.f;
        rs += A[j];
      }
      float inv = 1.f / fmaxf(rs, 1e-6f);
      #pragma unroll
      for (int j = 0; j < 4; ++j)
        Am[i][j] = (i == j) ? 0.f : A[j] * inv;
    }
  }
  __syncthreads();
  if (tid < 128) {
    int i = tid >> 5, c = tid & 31;
    h66[i][c] = fs[i][c];
    float s = 0.f;
    #pragma unroll
    for (int j = 0; j < 4; ++j) s += Am[i][j] * fs[j][c];
    h66[i][32 + c] = s;
  } else if (tid < 136) {
    int q = tid - 128;
    int i = q >> 1, d = q & 1;
    float s = 0.f;
    #pragma unroll
    for (int j = 0; j < 4; ++j) s += Am[i][j] * pd[i][j][d];
    h66[i][64 + d] = s;
  }
  __syncthreads();
  #pragma unroll
  for (int r = 0; r < 2; ++r) {
    int o = tid + 256 * r;
    const float* wrow = &gw[o * 66];
    float a0 = gb[o], a1 = a0, a2 = a0, a3 = a0;
    for (int c = 0; c < 66; ++c) {
      float wv = wrow[c];
      a0 = fmaf(h66[0][c], wv, a0);
      a1 = fmaf(h66[1][c], wv, a1);
      a2 = fmaf(h66[2][c], wv, a2);
      a3 = fmaf(h66[3][c], wv, a3);
    }
    hout[0][o] = fmaxf(a0, 0.f);
    hout[1][o] = fmaxf(a1, 0.f);
    hout[2][o] = fmaxf(a2, 0.f);
    hout[3][o] = fmaxf(a3, 0.f);
  }
  __syncthreads();
  if (tid < 192) {
    int gq = tid >> 4, l = tid & 15;
    int i = gq / 3, k = gq % 3;
    const float* wrow = (k < 2) ? &w4[k * 512] : w5;
    float s = 0.f;
    for (int o = l; o < 512; o += 16) s = fmaf(hout[i][o], wrow[o], s);
    #pragma unroll
    for (int d = 8; d >= 1; d >>= 1) s += __shfl_xor(s, d, 16);
    if (l == 0) {
      if (k < 2) out[(b * 4 + i) * 2 + k] = s + b4[k];
      else       out[1024 + b * 4 + i] = s + b5[0];
    }
  }
}

extern "C" void kernel_launch(void* const* d_in, const int* in_sizes, int n_in,
                              void* d_out, int out_size, void* d_ws, size_t ws_size,
                              hipStream_t stream) {
  const float* diffs  = (const float*)d_in[0];
  const float* states = (const float*)d_in[1];
  const float* w1 = (const float*)d_in[2];
  const float* b1 = (const float*)d_in[3];
  const float* w2 = (const float*)d_in[4];
  const float* b2 = (const float*)d_in[5];
  const float* gw = (const float*)d_in[6];
  const float* gb = (const float*)d_in[7];
  const float* w4 = (const float*)d_in[8];
  const float* b4 = (const float*)d_in[9];
  const float* w5 = (const float*)d_in[10];
  const float* b5 = (const float*)d_in[11];
  float* out = (float*)d_out;

  char* base = (char*)d_ws;
  f16*   w1f = (f16*)base;                    // 8192 B
  f16*   w2f = (f16*)(base + 8192);           // 26624 B -> 34816
  float* feat = (float*)(base + 34816);       // 65536 B -> 100352
  f16*   O1  = (f16*)(base + 100352);         // 512*4*57*60*4 f16 = 56.0 MB

  hipMemsetAsync(feat, 0, 512 * 32 * sizeof(float), stream);  // atomicMax identity
  k_repack<<<1, 256, 0, stream>>>(w1, w2, w1f, w2f);
  k_conv1<<<dim3(512, 8), 256, 0, stream>>>(states, w1f, b1, O1);
  k_conv2<<<dim3(512, 7), 256, 0, stream>>>(O1, w2f, b2, feat);
  k_head<<<128, 256, 0, stream>>>(diffs, feat, gw, gb, w4, b4, w5, b5, out);
}

// Round 7
// 99.714 us; speedup vs baseline: 1.2621x; 1.2590x over previous
//
#include <hip/hip_runtime.h>
#include <hip/hip_bf16.h>

#define H1 57   // 64-8+1
#define H2 53   // 57-5+1
#define XP 60   // padded x-stride of conv1 output (f16x4 units)

typedef _Float16 f16;
typedef _Float16 f16x4 __attribute__((ext_vector_type(4)));
typedef _Float16 f16x8 __attribute__((ext_vector_type(8)));
typedef float f32x4 __attribute__((ext_vector_type(4)));

// ---------------- weight repack + feat zero (grid 32) ----------------
// w1f[(tp*64+l)*8+j] = W1[oc=l&15][c=j&3][kh=tp][kw=4*(j>>2)+(l>>4)]  (c==3 -> 0)
// w2f[((tp*2+h)*64+l)*8+j] = W2[oc=(l&15)+16h][c=((l>>4)<<2)+(j&3)][tap=2tp+(j>>2)] (tap 25 -> 0)
// gwT2[c*256+t] = {gw[(2t)*66+c], gw[(2t+1)*66+c]}  (coalesced head GEMV)
__global__ __launch_bounds__(256) void k_repack(const float* __restrict__ w1,
    const float* __restrict__ w2, const float* __restrict__ gw,
    f16* __restrict__ w1f, f16* __restrict__ w2f,
    float2* __restrict__ gwT2, float* __restrict__ feat)
{
  const int tid = blockIdx.x * 256 + threadIdx.x;
  const int stride = 32 * 256;
  for (int i = tid; i < 8 * 64 * 8; i += stride) {
    int j = i & 7;
    int l = (i >> 3) & 63;
    int tp = i >> 9;
    int c = j & 3;
    int kw = 4 * (j >> 2) + (l >> 4);
    int oc = l & 15;
    float v = (c < 3) ? w1[((oc * 3 + c) * 8 + tp) * 8 + kw] : 0.f;
    w1f[i] = (f16)v;
  }
  for (int i = tid; i < 13 * 2 * 64 * 8; i += stride) {
    int j = i & 7;
    int l = (i >> 3) & 63;
    int h = (i >> 9) & 1;
    int tp = i >> 10;
    int tap = 2 * tp + (j >> 2);
    int c = ((l >> 4) << 2) + (j & 3);
    int oc = (l & 15) + (h << 4);
    float v = (tap < 25) ? w2[((oc * 16 + c) * 5 + tap / 5) * 5 + tap % 5] : 0.f;
    w2f[i] = (f16)v;
  }
  for (int i = tid; i < 66 * 256; i += stride) {
    int t = i & 255;
    int c = i >> 8;
    float2 v;
    v.x = gw[(2 * t) * 66 + c];
    v.y = gw[(2 * t + 1) * 66 + c];
    gwT2[i] = v;
  }
  for (int i = tid; i < 512 * 32; i += stride) feat[i] = 0.f;   // atomicMax identity
}

// ---------------- conv1 via MFMA implicit GEMM (round-6 form) ----------------
__global__ __launch_bounds__(256) void k_conv1(const float* __restrict__ in,
    const f16* __restrict__ w1f, const float* __restrict__ b1,
    f16* __restrict__ O1)
{
  __shared__ __align__(16) f16 sIn[15][72][4];   // 8640 B, c4 channels-last
  __shared__ __align__(16) f16 sT[4][64][20];    // 10240 B, per-wave transpose
  const int img = blockIdx.x;
  const int y0 = min((int)blockIdx.y * 8, 49);
  const int lane = threadIdx.x & 63;
  const int wv = threadIdx.x >> 6;

  f16x8 Bf[8];
  #pragma unroll
  for (int tp = 0; tp < 8; ++tp)
    Bf[tp] = *(const f16x8*)&w1f[(tp * 64 + lane) * 8];

  for (int i = threadIdx.x; i < 15 * 16; i += 256) {
    int y = i >> 4, xq = i & 15;
    const float* p0 = &in[(((size_t)img * 3 + 0) * 64 + (y0 + y)) * 64 + xq * 4];
    float4 v0 = *(const float4*)p0;
    float4 v1 = *(const float4*)(p0 + 4096);
    float4 v2 = *(const float4*)(p0 + 8192);
    float c0[4] = {v0.x, v0.y, v0.z, v0.w};
    float c1[4] = {v1.x, v1.y, v1.z, v1.w};
    float c2[4] = {v2.x, v2.y, v2.z, v2.w};
    #pragma unroll
    for (int q = 0; q < 4; ++q) {
      f16x4 tt = {(f16)c0[q], (f16)c1[q], (f16)c2[q], (f16)0.f};
      *(f16x4*)&sIn[y][xq * 4 + q][0] = tt;
    }
  }
  for (int i = threadIdx.x; i < 15 * 8; i += 256) {
    int y = i >> 3, xi = i & 7;
    *(f16x4*)&sIn[y][64 + xi][0] = (f16x4){(f16)0.f, (f16)0.f, (f16)0.f, (f16)0.f};
  }
  __syncthreads();

  const int g = lane >> 4;
  const int n16 = lane & 15;

  const float bias = b1[n16];
  f32x4 acc[2][4];
  #pragma unroll
  for (int r = 0; r < 2; ++r)
    #pragma unroll
    for (int xt = 0; xt < 4; ++xt)
      acc[r][xt] = (f32x4){bias, bias, bias, bias};

  #pragma unroll
  for (int tp = 0; tp < 8; ++tp) {        // kh = tp
    #pragma unroll
    for (int r = 0; r < 2; ++r) {
      const int row = 2 * wv + r + tp;
      #pragma unroll
      for (int xt = 0; xt < 4; ++xt) {
        const int px = xt * 16 + n16;
        f16x4 a0 = *(const f16x4*)&sIn[row][px + g][0];       // kw = g
        f16x4 a1 = *(const f16x4*)&sIn[row][px + 4 + g][0];   // kw = 4+g
        union { struct { f16x4 lo, hi; } pr; f16x8 v; } u;
        u.pr.lo = a0; u.pr.hi = a1;
        acc[r][xt] = __builtin_amdgcn_mfma_f32_16x16x32_f16(u.v, Bf[tp], acc[r][xt], 0, 0, 0);
      }
    }
  }

  #pragma unroll
  for (int r = 0; r < 2; ++r) {
    #pragma unroll
    for (int xt = 0; xt < 4; ++xt)
      #pragma unroll
      for (int q = 0; q < 4; ++q)
        sT[wv][xt * 16 + g * 4 + q][n16] = (f16)fmaxf(acc[r][xt][q], 0.f);
    const int yy = y0 + 2 * wv + r;
    if (lane < H1) {
      #pragma unroll
      for (int go = 0; go < 4; ++go) {
        f16x4 v = *(const f16x4*)&sT[wv][lane][go * 4];
        *(f16x4*)&O1[(((size_t)(img * 4 + go) * H1 + yy) * XP + lane) * 4] = v;
      }
    }
  }
}

// ---------------- conv2 via MFMA implicit GEMM + fused global max (round-4 form) ----
__global__ __launch_bounds__(256) void k_conv2(const f16* __restrict__ O1,
    const f16* __restrict__ w2f, const float* __restrict__ b2,
    float* __restrict__ feat)
{
  __shared__ __align__(16) f16 sW[13 * 2 * 64 * 8];          // 26624 B
  __shared__ __align__(16) f16 sI[4 * 12 * XP * 4 + 64];     // 23168 B
  __shared__ unsigned smax[32];
  const int img = blockIdx.x;
  const int y0 = min((int)blockIdx.y * 8, 45);
  if (threadIdx.x < 32) smax[threadIdx.x] = 0u;
  for (int i = threadIdx.x; i < 1664; i += 256)
    ((float4*)sW)[i] = ((const float4*)w2f)[i];
  for (int i = threadIdx.x; i < 4 * 360; i += 256) {
    int gg = i / 360, r = i % 360;
    ((float4*)sI)[gg * 360 + r] =
        *(const float4*)(O1 + (((size_t)(img * 4 + gg) * H1 + y0) * XP) * 4 + r * 8);
  }
  __syncthreads();

  const int lane = threadIdx.x & 63;
  const int wv = threadIdx.x >> 6;
  const int g = lane >> 4;
  const int n16 = lane & 15;

  f32x4 acc[2][4][2];
  #pragma unroll
  for (int r = 0; r < 2; ++r)
    #pragma unroll
    for (int xt = 0; xt < 4; ++xt)
      #pragma unroll
      for (int h = 0; h < 2; ++h)
        acc[r][xt][h] = (f32x4){0.f, 0.f, 0.f, 0.f};

  for (int tp = 0; tp < 13; ++tp) {
    f16x8 B0 = *(const f16x8*)&sW[((tp * 2 + 0) * 64 + lane) * 8];
    f16x8 B1 = *(const f16x8*)&sW[((tp * 2 + 1) * 64 + lane) * 8];
    const int t0 = 2 * tp;
    const int t1c = (t0 + 1 < 25) ? t0 + 1 : 0;   // tap 25 is zero-weight; clamp addr
    const int kh0 = t0 / 5, kw0 = t0 % 5;
    const int kh1 = t1c / 5, kw1 = t1c % 5;
    #pragma unroll
    for (int r = 0; r < 2; ++r) {
      const int yl = 2 * wv + r;
      const int row0 = (g * 12 + yl + kh0) * XP;
      const int row1 = (g * 12 + yl + kh1) * XP;
      #pragma unroll
      for (int xt = 0; xt < 4; ++xt) {
        const int px = xt * 16 + n16;
        f16x4 a0 = *(const f16x4*)&sI[(row0 + px + kw0) * 4];
        f16x4 a1 = *(const f16x4*)&sI[(row1 + px + kw1) * 4];
        union { struct { f16x4 lo, hi; } pr; f16x8 v; } u;
        u.pr.lo = a0; u.pr.hi = a1;
        acc[r][xt][0] = __builtin_amdgcn_mfma_f32_16x16x32_f16(u.v, B0, acc[r][xt][0], 0, 0, 0);
        acc[r][xt][1] = __builtin_amdgcn_mfma_f32_16x16x32_f16(u.v, B1, acc[r][xt][1], 0, 0, 0);
      }
    }
  }

  const float bias0 = b2[n16];
  const float bias1 = b2[n16 + 16];
  float m0 = 0.f, m1 = 0.f;
  #pragma unroll
  for (int r = 0; r < 2; ++r)
    #pragma unroll
    for (int xt = 0; xt < 4; ++xt)
      #pragma unroll
      for (int q = 0; q < 4; ++q) {
        int px = xt * 16 + g * 4 + q;
        if (px < H2) {
          m0 = fmaxf(m0, acc[r][xt][0][q] + bias0);
          m1 = fmaxf(m1, acc[r][xt][1][q] + bias1);
        }
      }
  m0 = fmaxf(m0, 0.f);
  m1 = fmaxf(m1, 0.f);
  m0 = fmaxf(m0, __shfl_xor(m0, 16, 64));
  m0 = fmaxf(m0, __shfl_xor(m0, 32, 64));
  m1 = fmaxf(m1, __shfl_xor(m1, 16, 64));
  m1 = fmaxf(m1, __shfl_xor(m1, 32, 64));
  if (g == 0) {
    atomicMax(&smax[n16], __float_as_uint(m0));
    atomicMax(&smax[n16 + 16], __float_as_uint(m1));
  }
  __syncthreads();
  if (threadIdx.x < 32)
    atomicMax((unsigned*)&feat[img * 32 + threadIdx.x], smax[threadIdx.x]);
}

// ---------------- head: adjacency + graph layer + MLP (coalesced GEMV) ----------------
__global__ __launch_bounds__(256) void k_head(const float* __restrict__ diffs,
    const float* __restrict__ feat, const float2* __restrict__ gwT2,
    const float* __restrict__ gb, const float* __restrict__ w4,
    const float* __restrict__ b4, const float* __restrict__ w5,
    const float* __restrict__ b5, float* __restrict__ out)
{
  __shared__ float h66[4][66];
  __shared__ float hout[4][512];
  __shared__ float Am[4][4];
  __shared__ float pd[4][4][2];
  __shared__ float fs[4][32];
  const int b = blockIdx.x;
  const int tid = threadIdx.x;
  if (tid < 128) {
    int i = tid >> 5, c = tid & 31;
    fs[i][c] = feat[(b * 4 + i) * 32 + c];
  }
  if (tid == 0) {
    float lx[4], ly[4];
    #pragma unroll
    for (int a = 0; a < 4; ++a) {
      lx[a] = diffs[(b * 4 + a) * 2];
      ly[a] = diffs[(b * 4 + a) * 2 + 1];
    }
    #pragma unroll
    for (int i = 0; i < 4; ++i) {
      float A[4];
      float rs = 0.f;
      #pragma unroll
      for (int j = 0; j < 4; ++j) {
        float dx = lx[i] - lx[j], dy = ly[i] - ly[j];
        pd[i][j][0] = dx;
        pd[i][j][1] = dy;
        float n = sqrtf(dx * dx + dy * dy);
        A[j] = (n < 1.41421356237309504880f) ? 1.f : 0.f;
        rs += A[j];
      }
      float inv = 1.f / fmaxf(rs, 1e-6f);
      #pragma unroll
      for (int j = 0; j < 4; ++j)
        Am[i][j] = (i == j) ? 0.f : A[j] * inv;
    }
  }
  __syncthreads();
  if (tid < 128) {
    int i = tid >> 5, c = tid & 31;
    h66[i][c] = fs[i][c];
    float s = 0.f;
    #pragma unroll
    for (int j = 0; j < 4; ++j) s += Am[i][j] * fs[j][c];
    h66[i][32 + c] = s;
  } else if (tid < 136) {
    int q = tid - 128;
    int i = q >> 1, d = q & 1;
    float s = 0.f;
    #pragma unroll
    for (int j = 0; j < 4; ++j) s += Am[i][j] * pd[i][j][d];
    h66[i][64 + d] = s;
  }
  __syncthreads();
  // coalesced GEMV: thread t owns outputs 2t, 2t+1; gwT2[c*256+t] is lane-contiguous
  {
    const float b0 = gb[2 * tid], b1g = gb[2 * tid + 1];
    float a[4][2];
    #pragma unroll
    for (int i = 0; i < 4; ++i) { a[i][0] = b0; a[i][1] = b1g; }
    #pragma unroll 6
    for (int c = 0; c < 66; ++c) {
      float2 w = gwT2[c * 256 + tid];
      #pragma unroll
      for (int i = 0; i < 4; ++i) {
        float h = h66[i][c];
        a[i][0] = fmaf(h, w.x, a[i][0]);
        a[i][1] = fmaf(h, w.y, a[i][1]);
      }
    }
    #pragma unroll
    for (int i = 0; i < 4; ++i) {
      float2 v;
      v.x = fmaxf(a[i][0], 0.f);
      v.y = fmaxf(a[i][1], 0.f);
      *(float2*)&hout[i][2 * tid] = v;
    }
  }
  __syncthreads();
  if (tid < 192) {
    int gq = tid >> 4, l = tid & 15;
    int i = gq / 3, k = gq % 3;
    const float* wrow = (k < 2) ? &w4[k * 512] : w5;
    float s = 0.f;
    for (int o = l; o < 512; o += 16) s = fmaf(hout[i][o], wrow[o], s);
    #pragma unroll
    for (int d = 8; d >= 1; d >>= 1) s += __shfl_xor(s, d, 16);
    if (l == 0) {
      if (k < 2) out[(b * 4 + i) * 2 + k] = s + b4[k];
      else       out[1024 + b * 4 + i] = s + b5[0];
    }
  }
}

extern "C" void kernel_launch(void* const* d_in, const int* in_sizes, int n_in,
                              void* d_out, int out_size, void* d_ws, size_t ws_size,
                              hipStream_t stream) {
  const float* diffs  = (const float*)d_in[0];
  const float* states = (const float*)d_in[1];
  const float* w1 = (const float*)d_in[2];
  const float* b1 = (const float*)d_in[3];
  const float* w2 = (const float*)d_in[4];
  const float* b2 = (const float*)d_in[5];
  const float* gw = (const float*)d_in[6];
  const float* gb = (const float*)d_in[7];
  const float* w4 = (const float*)d_in[8];
  const float* b4 = (const float*)d_in[9];
  const float* w5 = (const float*)d_in[10];
  const float* b5 = (const float*)d_in[11];
  float* out = (float*)d_out;

  char* base = (char*)d_ws;
  f16*    w1f  = (f16*)base;                    // 8192 B
  f16*    w2f  = (f16*)(base + 8192);           // 26624 B -> 34816
  float2* gwT2 = (float2*)(base + 34816);       // 135168 B -> 169984
  float*  feat = (float*)(base + 169984);       // 65536 B -> 235520
  f16*    O1   = (f16*)(base + 235520);         // 512*4*57*60*4 f16 = 56.0 MB

  k_repack<<<32, 256, 0, stream>>>(w1, w2, gw, w1f, w2f, gwT2, feat);
  k_conv1<<<dim3(512, 8), 256, 0, stream>>>(states, w1f, b1, O1);
  k_conv2<<<dim3(512, 7), 256, 0, stream>>>(O1, w2f, b2, feat);
  k_head<<<128, 256, 0, stream>>>(diffs, feat, gwT2, gb, w4, b4, w5, b5, out);
}

// Round 8
// 94.371 us; speedup vs baseline: 1.3336x; 1.0566x over previous
//
#include <hip/hip_runtime.h>
#include <hip/hip_bf16.h>

#define H1 57   // 64-8+1
#define H2 53   // 57-5+1
#define XP 60   // padded x-stride of conv1 output (x slots)

typedef _Float16 f16;
typedef _Float16 f16x4 __attribute__((ext_vector_type(4)));
typedef _Float16 f16x8 __attribute__((ext_vector_type(8)));
typedef float f32x4 __attribute__((ext_vector_type(4)));
typedef float f32x16 __attribute__((ext_vector_type(16)));

// ---------------- weight repack + gw transpose + feat zero (grid 32) ----------------
// w1f[(tp*64+l)*8+j] = W1[oc=l&15][c=j&3][kh=tp][kw=4*(j>>2)+(l>>4)]  (c==3 -> 0)
// w2f (32x32x16 fragments): w2f[(tap*64+l)*8+j] = W2[oc=l&31][ch=(l>>5)*8+j][tap]
// gwT2[c*256+t] = {gw[(2t)*66+c], gw[(2t+1)*66+c]}
__global__ __launch_bounds__(256) void k_repack(const float* __restrict__ w1,
    const float* __restrict__ w2, const float* __restrict__ gw,
    f16* __restrict__ w1f, f16* __restrict__ w2f,
    float2* __restrict__ gwT2, float* __restrict__ feat)
{
  const int tid = blockIdx.x * 256 + threadIdx.x;
  const int stride = 32 * 256;
  for (int i = tid; i < 8 * 64 * 8; i += stride) {
    int j = i & 7;
    int l = (i >> 3) & 63;
    int tp = i >> 9;
    int c = j & 3;
    int kw = 4 * (j >> 2) + (l >> 4);
    int oc = l & 15;
    float v = (c < 3) ? w1[((oc * 3 + c) * 8 + tp) * 8 + kw] : 0.f;
    w1f[i] = (f16)v;
  }
  for (int i = tid; i < 25 * 64 * 8; i += stride) {
    int j = i & 7;
    int l = (i >> 3) & 63;
    int tap = i >> 9;
    int oc = l & 31;
    int ch = ((l >> 5) << 3) + j;
    w2f[i] = (f16)w2[((oc * 16 + ch) * 5 + tap / 5) * 5 + tap % 5];
  }
  for (int i = tid; i < 66 * 256; i += stride) {
    int t = i & 255;
    int c = i >> 8;
    float2 v;
    v.x = gw[(2 * t) * 66 + c];
    v.y = gw[(2 * t + 1) * 66 + c];
    gwT2[i] = v;
  }
  for (int i = tid; i < 512 * 32; i += stride) feat[i] = 0.f;   // atomicMax identity
}

// ---------------- conv1 via MFMA implicit GEMM -> O1[img][y][x][c16] ----------------
__global__ __launch_bounds__(256) void k_conv1(const float* __restrict__ in,
    const f16* __restrict__ w1f, const float* __restrict__ b1,
    f16* __restrict__ O1)
{
  __shared__ __align__(16) f16 sIn[15][72][4];   // 8640 B, c4 channels-last
  __shared__ __align__(16) f16 sT[4][64][20];    // 10240 B, per-wave transpose
  const int img = blockIdx.x;
  const int y0 = min((int)blockIdx.y * 8, 49);
  const int lane = threadIdx.x & 63;
  const int wv = threadIdx.x >> 6;

  f16x8 Bf[8];
  #pragma unroll
  for (int tp = 0; tp < 8; ++tp)
    Bf[tp] = *(const f16x8*)&w1f[(tp * 64 + lane) * 8];

  for (int i = threadIdx.x; i < 15 * 16; i += 256) {
    int y = i >> 4, xq = i & 15;
    const float* p0 = &in[(((size_t)img * 3 + 0) * 64 + (y0 + y)) * 64 + xq * 4];
    float4 v0 = *(const float4*)p0;
    float4 v1 = *(const float4*)(p0 + 4096);
    float4 v2 = *(const float4*)(p0 + 8192);
    float c0[4] = {v0.x, v0.y, v0.z, v0.w};
    float c1[4] = {v1.x, v1.y, v1.z, v1.w};
    float c2[4] = {v2.x, v2.y, v2.z, v2.w};
    #pragma unroll
    for (int q = 0; q < 4; ++q) {
      f16x4 tt = {(f16)c0[q], (f16)c1[q], (f16)c2[q], (f16)0.f};
      *(f16x4*)&sIn[y][xq * 4 + q][0] = tt;
    }
  }
  for (int i = threadIdx.x; i < 15 * 8; i += 256) {
    int y = i >> 3, xi = i & 7;
    *(f16x4*)&sIn[y][64 + xi][0] = (f16x4){(f16)0.f, (f16)0.f, (f16)0.f, (f16)0.f};
  }
  __syncthreads();

  const int g = lane >> 4;
  const int n16 = lane & 15;

  const float bias = b1[n16];
  f32x4 acc[2][4];
  #pragma unroll
  for (int r = 0; r < 2; ++r)
    #pragma unroll
    for (int xt = 0; xt < 4; ++xt)
      acc[r][xt] = (f32x4){bias, bias, bias, bias};

  #pragma unroll
  for (int tp = 0; tp < 8; ++tp) {        // kh = tp
    #pragma unroll
    for (int r = 0; r < 2; ++r) {
      const int row = 2 * wv + r + tp;
      #pragma unroll
      for (int xt = 0; xt < 4; ++xt) {
        const int px = xt * 16 + n16;
        f16x4 a0 = *(const f16x4*)&sIn[row][px + g][0];       // kw = g
        f16x4 a1 = *(const f16x4*)&sIn[row][px + 4 + g][0];   // kw = 4+g
        union { struct { f16x4 lo, hi; } pr; f16x8 v; } u;
        u.pr.lo = a0; u.pr.hi = a1;
        acc[r][xt] = __builtin_amdgcn_mfma_f32_16x16x32_f16(u.v, Bf[tp], acc[r][xt], 0, 0, 0);
      }
    }
  }

  // epilogue: relu, per-wave LDS transpose (oc-major -> c16), coalesced 32B/lane store
  #pragma unroll
  for (int r = 0; r < 2; ++r) {
    #pragma unroll
    for (int xt = 0; xt < 4; ++xt)
      #pragma unroll
      for (int q = 0; q < 4; ++q)
        sT[wv][xt * 16 + g * 4 + q][n16] = (f16)fmaxf(acc[r][xt][q], 0.f);
    const int yy = y0 + 2 * wv + r;
    if (lane < H1) {
      f16x4 v0 = *(const f16x4*)&sT[wv][lane][0];
      f16x4 v1 = *(const f16x4*)&sT[wv][lane][4];
      f16x4 v2 = *(const f16x4*)&sT[wv][lane][8];
      f16x4 v3 = *(const f16x4*)&sT[wv][lane][12];
      union { struct { f16x4 a, b; } pr; f16x8 v; } lo, hi;
      lo.pr.a = v0; lo.pr.b = v1;
      hi.pr.a = v2; hi.pr.b = v3;
      f16* dst = &O1[(((size_t)img * H1 + yy) * XP + lane) * 16];
      *(f16x8*)dst = lo.v;
      *(f16x8*)(dst + 8) = hi.v;
    }
  }
}

// ---------------- conv2 via 32x32x16 MFMA implicit GEMM + fused global max --------
// grid (512, 7): y0 in {0,8,...,40,45}. block 256 = 4 waves.
// K-step = 1 tap x 16 ch (25 steps). Lane: oc = lane&31 (B col / D col),
// px-row = lane&31 (A row), G = lane>>5 selects channel octet.
// LDS sI[12 y][2 oct][60 x][8 c] -> A-read = one lane-linear ds_read_b128.
__global__ __launch_bounds__(256) void k_conv2(const f16* __restrict__ O1,
    const f16* __restrict__ w2f, const float* __restrict__ b2,
    float* __restrict__ feat)
{
  __shared__ __align__(16) f16 sW[25 * 64 * 8];            // 25600 B
  __shared__ __align__(16) f16 sI[12 * 2 * 60 * 8 + 64];   // 23168 B
  __shared__ unsigned smax[32];
  const int img = blockIdx.x;
  const int y0 = min((int)blockIdx.y * 8, 45);
  if (threadIdx.x < 32) smax[threadIdx.x] = 0u;
  for (int i = threadIdx.x; i < 1600; i += 256)
    ((float4*)sW)[i] = ((const float4*)w2f)[i];
  // sI slot i -> y = i/120, oct = (i/60)%2, x = i%60 ; src O1[img][y0+y][x][oct*8..]
  for (int i = threadIdx.x; i < 1440; i += 256) {
    int y = i / 120;
    int rem = i - y * 120;
    int oct = rem / 60;
    int x = rem - oct * 60;
    ((float4*)sI)[i] =
        *(const float4*)(O1 + (((size_t)img * H1 + y0 + y) * XP + x) * 16 + oct * 8);
  }
  __syncthreads();

  const int lane = threadIdx.x & 63;
  const int wv = threadIdx.x >> 6;
  const int m32 = lane & 31;      // A row (px-in-tile) / B,D col (oc)
  const int G = lane >> 5;        // channel octet

  const float bias = b2[m32];
  f32x16 acc[2][2];               // [r][half]
  #pragma unroll
  for (int r = 0; r < 2; ++r)
    #pragma unroll
    for (int h = 0; h < 2; ++h)
      #pragma unroll
      for (int q = 0; q < 16; ++q)
        acc[r][h][q] = bias;

  // hoisted A bases (f16 units): ((ylocal*2 + G)*60 + h*32 + m32)*8
  const f16* pA[2][2];
  #pragma unroll
  for (int r = 0; r < 2; ++r)
    #pragma unroll
    for (int h = 0; h < 2; ++h)
      pA[r][h] = &sI[(((2 * wv + r) * 2 + G) * XP + h * 32 + m32) * 8];
  const f16* pB = &sW[lane * 8];

  #pragma unroll
  for (int tap = 0; tap < 25; ++tap) {
    const int kh = tap / 5, kw = tap % 5;
    const int off = (kh * 2 * XP + kw) * 8;    // const imm after unroll
    f16x8 Bv = *(const f16x8*)(pB + tap * 512);
    #pragma unroll
    for (int r = 0; r < 2; ++r)
      #pragma unroll
      for (int h = 0; h < 2; ++h) {
        f16x8 Av = *(const f16x8*)(pA[r][h] + off);
        acc[r][h] = __builtin_amdgcn_mfma_f32_32x32x16_f16(Av, Bv, acc[r][h], 0, 0, 0);
      }
  }

  // epilogue: mask invalid px, relu, per-oc max; D row=(q&3)+8*(q>>2)+4*G, col=oc
  float m = 0.f;
  #pragma unroll
  for (int r = 0; r < 2; ++r)
    #pragma unroll
    for (int h = 0; h < 2; ++h)
      #pragma unroll
      for (int q = 0; q < 16; ++q) {
        int row = (q & 3) + 8 * (q >> 2) + 4 * G;
        int px = h * 32 + row;
        if (px < H2) m = fmaxf(m, acc[r][h][q]);
      }
  m = fmaxf(m, 0.f);   // relu
  m = fmaxf(m, __shfl_xor(m, 32, 64));
  if (lane < 32) atomicMax(&smax[m32], __float_as_uint(m));
  __syncthreads();
  if (threadIdx.x < 32)
    atomicMax((unsigned*)&feat[img * 32 + threadIdx.x], smax[threadIdx.x]);
}

// ---------------- head: adjacency + graph layer + MLP (coalesced GEMV) ----------------
__global__ __launch_bounds__(256) void k_head(const float* __restrict__ diffs,
    const float* __restrict__ feat, const float2* __restrict__ gwT2,
    const float* __restrict__ gb, const float* __restrict__ w4,
    const float* __restrict__ b4, const float* __restrict__ w5,
    const float* __restrict__ b5, float* __restrict__ out)
{
  __shared__ float h66[4][66];
  __shared__ float hout[4][512];
  __shared__ float Am[4][4];
  __shared__ float pd[4][4][2];
  __shared__ float fs[4][32];
  const int b = blockIdx.x;
  const int tid = threadIdx.x;
  if (tid < 128) {
    int i = tid >> 5, c = tid & 31;
    fs[i][c] = feat[(b * 4 + i) * 32 + c];
  }
  if (tid == 0) {
    float lx[4], ly[4];
    #pragma unroll
    for (int a = 0; a < 4; ++a) {
      lx[a] = diffs[(b * 4 + a) * 2];
      ly[a] = diffs[(b * 4 + a) * 2 + 1];
    }
    #pragma unroll
    for (int i = 0; i < 4; ++i) {
      float A[4];
      float rs = 0.f;
      #pragma unroll
      for (int j = 0; j < 4; ++j) {
        float dx = lx[i] - lx[j], dy = ly[i] - ly[j];
        pd[i][j][0] = dx;
        pd[i][j][1] = dy;
        float n = sqrtf(dx * dx + dy * dy);
        A[j] = (n < 1.41421356237309504880f) ? 1.f : 0.f;
        rs += A[j];
      }
      float inv = 1.f / fmaxf(rs, 1e-6f);
      #pragma unroll
      for (int j = 0; j < 4; ++j)
        Am[i][j] = (i == j) ? 0.f : A[j] * inv;
    }
  }
  __syncthreads();
  if (tid < 128) {
    int i = tid >> 5, c = tid & 31;
    h66[i][c] = fs[i][c];
    float s = 0.f;
    #pragma unroll
    for (int j = 0; j < 4; ++j) s += Am[i][j] * fs[j][c];
    h66[i][32 + c] = s;
  } else if (tid < 136) {
    int q = tid - 128;
    int i = q >> 1, d = q & 1;
    float s = 0.f;
    #pragma unroll
    for (int j = 0; j < 4; ++j) s += Am[i][j] * pd[i][j][d];
    h66[i][64 + d] = s;
  }
  __syncthreads();
  {
    const float b0 = gb[2 * tid], b1g = gb[2 * tid + 1];
    float a[4][2];
    #pragma unroll
    for (int i = 0; i < 4; ++i) { a[i][0] = b0; a[i][1] = b1g; }
    #pragma unroll 6
    for (int c = 0; c < 66; ++c) {
      float2 w = gwT2[c * 256 + tid];
      #pragma unroll
      for (int i = 0; i < 4; ++i) {
        float h = h66[i][c];
        a[i][0] = fmaf(h, w.x, a[i][0]);
        a[i][1] = fmaf(h, w.y, a[i][1]);
      }
    }
    #pragma unroll
    for (int i = 0; i < 4; ++i) {
      float2 v;
      v.x = fmaxf(a[i][0], 0.f);
      v.y = fmaxf(a[i][1], 0.f);
      *(float2*)&hout[i][2 * tid] = v;
    }
  }
  __syncthreads();
  if (tid < 192) {
    int gq = tid >> 4, l = tid & 15;
    int i = gq / 3, k = gq % 3;
    const float* wrow = (k < 2) ? &w4[k * 512] : w5;
    float s = 0.f;
    for (int o = l; o < 512; o += 16) s = fmaf(hout[i][o], wrow[o], s);
    #pragma unroll
    for (int d = 8; d >= 1; d >>= 1) s += __shfl_xor(s, d, 16);
    if (l == 0) {
      if (k < 2) out[(b * 4 + i) * 2 + k] = s + b4[k];
      else       out[1024 + b * 4 + i] = s + b5[0];
    }
  }
}

extern "C" void kernel_launch(void* const* d_in, const int* in_sizes, int n_in,
                              void* d_out, int out_size, void* d_ws, size_t ws_size,
                              hipStream_t stream) {
  const float* diffs  = (const float*)d_in[0];
  const float* states = (const float*)d_in[1];
  const float* w1 = (const float*)d_in[2];
  const float* b1 = (const float*)d_in[3];
  const float* w2 = (const float*)d_in[4];
  const float* b2 = (const float*)d_in[5];
  const float* gw = (const float*)d_in[6];
  const float* gb = (const float*)d_in[7];
  const float* w4 = (const float*)d_in[8];
  const float* b4 = (const float*)d_in[9];
  const float* w5 = (const float*)d_in[10];
  const float* b5 = (const float*)d_in[11];
  float* out = (float*)d_out;

  char* base = (char*)d_ws;
  f16*    w1f  = (f16*)base;                    // 8192 B
  f16*    w2f  = (f16*)(base + 8192);           // 25600 B -> ends 33792
  float2* gwT2 = (float2*)(base + 34816);       // 135168 B -> 169984
  float*  feat = (float*)(base + 169984);       // 65536 B -> 235520
  f16*    O1   = (f16*)(base + 235520);         // 512*57*60*16 f16 = 56.0 MB

  k_repack<<<32, 256, 0, stream>>>(w1, w2, gw, w1f, w2f, gwT2, feat);
  k_conv1<<<dim3(512, 8), 256, 0, stream>>>(states, w1f, b1, O1);
  k_conv2<<<dim3(512, 7), 256, 0, stream>>>(O1, w2f, b2, feat);
  k_head<<<128, 256, 0, stream>>>(diffs, feat, gwT2, gb, w4, b4, w5, b5, out);
}

// Round 9
// 90.007 us; speedup vs baseline: 1.3982x; 1.0485x over previous
//
#include <hip/hip_runtime.h>
#include <hip/hip_bf16.h>

#define H1 57   // 64-8+1
#define H2 53   // 57-5+1
#define XP 60   // padded x-stride of conv1 output (x slots)

typedef _Float16 f16;
typedef _Float16 f16x4 __attribute__((ext_vector_type(4)));
typedef _Float16 f16x8 __attribute__((ext_vector_type(8)));
typedef float f32x4 __attribute__((ext_vector_type(4)));
typedef float f32x16 __attribute__((ext_vector_type(16)));

// ---------------- weight repack + gw transpose + feat zero (grid 32) ----------------
// w1f[(tp*64+l)*8+j] = W1[oc=l&15][c=j&3][kh=tp][kw=2*(l>>4)+(j>>2)]  (c==3 -> 0)
//   (kw mapping chosen so A-frag = 8 contiguous f16 -> ds_read2_b64)
// w2f (32x32x16 fragments): w2f[(tap*64+l)*8+j] = W2[oc=l&31][ch=(l>>5)*8+j][tap]
// gwT2[c*256+t] = {gw[(2t)*66+c], gw[(2t+1)*66+c]}
__global__ __launch_bounds__(256) void k_repack(const float* __restrict__ w1,
    const float* __restrict__ w2, const float* __restrict__ gw,
    f16* __restrict__ w1f, f16* __restrict__ w2f,
    float2* __restrict__ gwT2, float* __restrict__ feat)
{
  const int tid = blockIdx.x * 256 + threadIdx.x;
  const int stride = 32 * 256;
  for (int i = tid; i < 8 * 64 * 8; i += stride) {
    int j = i & 7;
    int l = (i >> 3) & 63;
    int tp = i >> 9;
    int c = j & 3;
    int kw = 2 * (l >> 4) + (j >> 2);
    int oc = l & 15;
    float v = (c < 3) ? w1[((oc * 3 + c) * 8 + tp) * 8 + kw] : 0.f;
    w1f[i] = (f16)v;
  }
  for (int i = tid; i < 25 * 64 * 8; i += stride) {
    int j = i & 7;
    int l = (i >> 3) & 63;
    int tap = i >> 9;
    int oc = l & 31;
    int ch = ((l >> 5) << 3) + j;
    w2f[i] = (f16)w2[((oc * 16 + ch) * 5 + tap / 5) * 5 + tap % 5];
  }
  for (int i = tid; i < 66 * 256; i += stride) {
    int t = i & 255;
    int c = i >> 8;
    float2 v;
    v.x = gw[(2 * t) * 66 + c];
    v.y = gw[(2 * t + 1) * 66 + c];
    gwT2[i] = v;
  }
  for (int i = tid; i < 512 * 32; i += stride) feat[i] = 0.f;   // atomicMax identity
}

// ---------------- conv1 via MFMA implicit GEMM -> O1[img][y][x][c16] ----------------
// A-frag = one 8-f16 span (slots px+2g, px+2g+1) -> fusable ds_read2_b64.
__global__ __launch_bounds__(256) void k_conv1(const float* __restrict__ in,
    const f16* __restrict__ w1f, const float* __restrict__ b1,
    f16* __restrict__ O1)
{
  __shared__ __align__(16) f16 sIn[15][72][4];   // 8640 B, c4 channels-last
  __shared__ __align__(16) f16 sT[4][64][20];    // 10240 B, per-wave transpose
  const int img = blockIdx.x;
  const int y0 = min((int)blockIdx.y * 8, 49);
  const int lane = threadIdx.x & 63;
  const int wv = threadIdx.x >> 6;

  f16x8 Bf[8];
  #pragma unroll
  for (int tp = 0; tp < 8; ++tp)
    Bf[tp] = *(const f16x8*)&w1f[(tp * 64 + lane) * 8];

  for (int i = threadIdx.x; i < 15 * 16; i += 256) {
    int y = i >> 4, xq = i & 15;
    const float* p0 = &in[(((size_t)img * 3 + 0) * 64 + (y0 + y)) * 64 + xq * 4];
    float4 v0 = *(const float4*)p0;
    float4 v1 = *(const float4*)(p0 + 4096);
    float4 v2 = *(const float4*)(p0 + 8192);
    float c0[4] = {v0.x, v0.y, v0.z, v0.w};
    float c1[4] = {v1.x, v1.y, v1.z, v1.w};
    float c2[4] = {v2.x, v2.y, v2.z, v2.w};
    #pragma unroll
    for (int q = 0; q < 4; ++q) {
      f16x4 tt = {(f16)c0[q], (f16)c1[q], (f16)c2[q], (f16)0.f};
      *(f16x4*)&sIn[y][xq * 4 + q][0] = tt;
    }
  }
  for (int i = threadIdx.x; i < 15 * 8; i += 256) {
    int y = i >> 3, xi = i & 7;
    *(f16x4*)&sIn[y][64 + xi][0] = (f16x4){(f16)0.f, (f16)0.f, (f16)0.f, (f16)0.f};
  }
  __syncthreads();

  const int g = lane >> 4;
  const int n16 = lane & 15;

  const float bias = b1[n16];
  f32x4 acc[2][4];
  #pragma unroll
  for (int r = 0; r < 2; ++r)
    #pragma unroll
    for (int xt = 0; xt < 4; ++xt)
      acc[r][xt] = (f32x4){bias, bias, bias, bias};

  #pragma unroll
  for (int tp = 0; tp < 8; ++tp) {        // kh = tp
    #pragma unroll
    for (int r = 0; r < 2; ++r) {
      const int row = 2 * wv + r + tp;
      #pragma unroll
      for (int xt = 0; xt < 4; ++xt) {
        const int px = xt * 16 + n16;
        // kw = 2g + (j>>2): two adjacent b64 slots -> ds_read2_b64
        f16x4 a0 = *(const f16x4*)&sIn[row][px + 2 * g][0];
        f16x4 a1 = *(const f16x4*)&sIn[row][px + 2 * g + 1][0];
        union { struct { f16x4 lo, hi; } pr; f16x8 v; } u;
        u.pr.lo = a0; u.pr.hi = a1;
        acc[r][xt] = __builtin_amdgcn_mfma_f32_16x16x32_f16(u.v, Bf[tp], acc[r][xt], 0, 0, 0);
      }
    }
  }

  // epilogue: relu, per-wave LDS transpose (oc-major -> c16), coalesced 32B/lane store
  #pragma unroll
  for (int r = 0; r < 2; ++r) {
    #pragma unroll
    for (int xt = 0; xt < 4; ++xt)
      #pragma unroll
      for (int q = 0; q < 4; ++q)
        sT[wv][xt * 16 + g * 4 + q][n16] = (f16)fmaxf(acc[r][xt][q], 0.f);
    const int yy = y0 + 2 * wv + r;
    if (lane < H1) {
      f16x4 v0 = *(const f16x4*)&sT[wv][lane][0];
      f16x4 v1 = *(const f16x4*)&sT[wv][lane][4];
      f16x4 v2 = *(const f16x4*)&sT[wv][lane][8];
      f16x4 v3 = *(const f16x4*)&sT[wv][lane][12];
      union { struct { f16x4 a, b; } pr; f16x8 v; } lo, hi;
      lo.pr.a = v0; lo.pr.b = v1;
      hi.pr.a = v2; hi.pr.b = v3;
      f16* dst = &O1[(((size_t)img * H1 + yy) * XP + lane) * 16];
      *(f16x8*)dst = lo.v;
      *(f16x8*)(dst + 8) = hi.v;
    }
  }
}

// ---------------- conv2 via 32x32x16 MFMA, hybrid reg/LDS B + fused global max ----
// grid (512, 7): y0 in {0,8,...,40,45}. block 256 = 4 waves.
// Taps 0-7: B-fragments preloaded to registers from global (coalesced, latency
// hidden under sI staging). Taps 8-24: B staged in LDS (17 KB).
// LDS total ~39.9 KB -> 4 blocks/CU; launch_bounds(256,4) caps VGPR at 128.
__global__ __launch_bounds__(256, 4) void k_conv2(const f16* __restrict__ O1,
    const f16* __restrict__ w2f, const float* __restrict__ b2,
    float* __restrict__ feat)
{
  __shared__ __align__(16) f16 sW[17 * 64 * 8];            // 17408 B (taps 8..24)
  __shared__ __align__(16) f16 sI[12 * 2 * 60 * 8 + 64];   // 23168 B
  __shared__ unsigned smax[32];
  const int img = blockIdx.x;
  const int y0 = min((int)blockIdx.y * 8, 45);
  const int lane = threadIdx.x & 63;
  const int wv = threadIdx.x >> 6;
  if (threadIdx.x < 32) smax[threadIdx.x] = 0u;

  // B-frags taps 0-7 from global (issued first; staging below hides latency)
  f16x8 Br[8];
  const f16* pBg = &w2f[lane * 8];
  #pragma unroll
  for (int t = 0; t < 8; ++t)
    Br[t] = *(const f16x8*)(pBg + t * 512);

  for (int i = threadIdx.x; i < 17 * 64; i += 256)
    ((float4*)sW)[i] = ((const float4*)w2f)[8 * 64 + i];
  // sI slot i -> y = i/120, oct = (i/60)%2, x = i%60 ; src O1[img][y0+y][x][oct*8..]
  for (int i = threadIdx.x; i < 1440; i += 256) {
    int y = i / 120;
    int rem = i - y * 120;
    int oct = rem / 60;
    int x = rem - oct * 60;
    ((float4*)sI)[i] =
        *(const float4*)(O1 + (((size_t)img * H1 + y0 + y) * XP + x) * 16 + oct * 8);
  }
  __syncthreads();

  const int m32 = lane & 31;      // A row (px-in-tile) / B,D col (oc)
  const int G = lane >> 5;        // channel octet

  const float bias = b2[m32];
  f32x16 acc[2][2];               // [r][half]
  #pragma unroll
  for (int r = 0; r < 2; ++r)
    #pragma unroll
    for (int h = 0; h < 2; ++h)
      #pragma unroll
      for (int q = 0; q < 16; ++q)
        acc[r][h][q] = bias;

  const f16* pA[2][2];
  #pragma unroll
  for (int r = 0; r < 2; ++r)
    #pragma unroll
    for (int h = 0; h < 2; ++h)
      pA[r][h] = &sI[(((2 * wv + r) * 2 + G) * XP + h * 32 + m32) * 8];
  const f16* pB = &sW[lane * 8];

  #pragma unroll
  for (int tap = 0; tap < 25; ++tap) {
    const int kh = tap / 5, kw = tap % 5;
    const int off = (kh * 2 * XP + kw) * 8;    // const imm after unroll
    f16x8 Bv = (tap < 8) ? Br[tap] : *(const f16x8*)(pB + (tap - 8) * 512);
    #pragma unroll
    for (int r = 0; r < 2; ++r)
      #pragma unroll
      for (int h = 0; h < 2; ++h) {
        f16x8 Av = *(const f16x8*)(pA[r][h] + off);
        acc[r][h] = __builtin_amdgcn_mfma_f32_32x32x16_f16(Av, Bv, acc[r][h], 0, 0, 0);
      }
  }

  // epilogue: mask invalid px, relu, per-oc max; D row=(q&3)+8*(q>>2)+4*G, col=oc
  float m = 0.f;
  #pragma unroll
  for (int r = 0; r < 2; ++r)
    #pragma unroll
    for (int h = 0; h < 2; ++h)
      #pragma unroll
      for (int q = 0; q < 16; ++q) {
        int row = (q & 3) + 8 * (q >> 2) + 4 * G;
        int px = h * 32 + row;
        if (px < H2) m = fmaxf(m, acc[r][h][q]);
      }
  m = fmaxf(m, 0.f);   // relu
  m = fmaxf(m, __shfl_xor(m, 32, 64));
  if (lane < 32) atomicMax(&smax[m32], __float_as_uint(m));
  __syncthreads();
  if (threadIdx.x < 32)
    atomicMax((unsigned*)&feat[img * 32 + threadIdx.x], smax[threadIdx.x]);
}

// ---------------- head: adjacency + graph layer + MLP (coalesced GEMV) ----------------
__global__ __launch_bounds__(256) void k_head(const float* __restrict__ diffs,
    const float* __restrict__ feat, const float2* __restrict__ gwT2,
    const float* __restrict__ gb, const float* __restrict__ w4,
    const float* __restrict__ b4, const float* __restrict__ w5,
    const float* __restrict__ b5, float* __restrict__ out)
{
  __shared__ float h66[4][66];
  __shared__ float hout[4][512];
  __shared__ float Am[4][4];
  __shared__ float pd[4][4][2];
  __shared__ float fs[4][32];
  const int b = blockIdx.x;
  const int tid = threadIdx.x;
  if (tid < 128) {
    int i = tid >> 5, c = tid & 31;
    fs[i][c] = feat[(b * 4 + i) * 32 + c];
  }
  if (tid == 0) {
    float lx[4], ly[4];
    #pragma unroll
    for (int a = 0; a < 4; ++a) {
      lx[a] = diffs[(b * 4 + a) * 2];
      ly[a] = diffs[(b * 4 + a) * 2 + 1];
    }
    #pragma unroll
    for (int i = 0; i < 4; ++i) {
      float A[4];
      float rs = 0.f;
      #pragma unroll
      for (int j = 0; j < 4; ++j) {
        float dx = lx[i] - lx[j], dy = ly[i] - ly[j];
        pd[i][j][0] = dx;
        pd[i][j][1] = dy;
        float n = sqrtf(dx * dx + dy * dy);
        A[j] = (n < 1.41421356237309504880f) ? 1.f : 0.f;
        rs += A[j];
      }
      float inv = 1.f / fmaxf(rs, 1e-6f);
      #pragma unroll
      for (int j = 0; j < 4; ++j)
        Am[i][j] = (i == j) ? 0.f : A[j] * inv;
    }
  }
  __syncthreads();
  if (tid < 128) {
    int i = tid >> 5, c = tid & 31;
    h66[i][c] = fs[i][c];
    float s = 0.f;
    #pragma unroll
    for (int j = 0; j < 4; ++j) s += Am[i][j] * fs[j][c];
    h66[i][32 + c] = s;
  } else if (tid < 136) {
    int q = tid - 128;
    int i = q >> 1, d = q & 1;
    float s = 0.f;
    #pragma unroll
    for (int j = 0; j < 4; ++j) s += Am[i][j] * pd[i][j][d];
    h66[i][64 + d] = s;
  }
  __syncthreads();
  {
    const float b0 = gb[2 * tid], b1g = gb[2 * tid + 1];
    float a[4][2];
    #pragma unroll
    for (int i = 0; i < 4; ++i) { a[i][0] = b0; a[i][1] = b1g; }
    #pragma unroll 6
    for (int c = 0; c < 66; ++c) {
      float2 w = gwT2[c * 256 + tid];
      #pragma unroll
      for (int i = 0; i < 4; ++i) {
        float h = h66[i][c];
        a[i][0] = fmaf(h, w.x, a[i][0]);
        a[i][1] = fmaf(h, w.y, a[i][1]);
      }
    }
    #pragma unroll
    for (int i = 0; i < 4; ++i) {
      float2 v;
      v.x = fmaxf(a[i][0], 0.f);
      v.y = fmaxf(a[i][1], 0.f);
      *(float2*)&hout[i][2 * tid] = v;
    }
  }
  __syncthreads();
  if (tid < 192) {
    int gq = tid >> 4, l = tid & 15;
    int i = gq / 3, k = gq % 3;
    const float* wrow = (k < 2) ? &w4[k * 512] : w5;
    float s = 0.f;
    for (int o = l; o < 512; o += 16) s = fmaf(hout[i][o], wrow[o], s);
    #pragma unroll
    for (int d = 8; d >= 1; d >>= 1) s += __shfl_xor(s, d, 16);
    if (l == 0) {
      if (k < 2) out[(b * 4 + i) * 2 + k] = s + b4[k];
      else       out[1024 + b * 4 + i] = s + b5[0];
    }
  }
}

extern "C" void kernel_launch(void* const* d_in, const int* in_sizes, int n_in,
                              void* d_out, int out_size, void* d_ws, size_t ws_size,
                              hipStream_t stream) {
  const float* diffs  = (const float*)d_in[0];
  const float* states = (const float*)d_in[1];
  const float* w1 = (const float*)d_in[2];
  const float* b1 = (const float*)d_in[3];
  const float* w2 = (const float*)d_in[4];
  const float* b2 = (const float*)d_in[5];
  const float* gw = (const float*)d_in[6];
  const float* gb = (const float*)d_in[7];
  const float* w4 = (const float*)d_in[8];
  const float* b4 = (const float*)d_in[9];
  const float* w5 = (const float*)d_in[10];
  const float* b5 = (const float*)d_in[11];
  float* out = (float*)d_out;

  char* base = (char*)d_ws;
  f16*    w1f  = (f16*)base;                    // 8192 B
  f16*    w2f  = (f16*)(base + 8192);           // 25600 B -> ends 33792
  float2* gwT2 = (float2*)(base + 34816);       // 135168 B -> 169984
  float*  feat = (float*)(base + 169984);       // 65536 B -> 235520
  f16*    O1   = (f16*)(base + 235520);         // 512*57*60*16 f16 = 56.0 MB

  k_repack<<<32, 256, 0, stream>>>(w1, w2, gw, w1f, w2f, gwT2, feat);
  k_conv1<<<dim3(512, 8), 256, 0, stream>>>(states, w1f, b1, O1);
  k_conv2<<<dim3(512, 7), 256, 0, stream>>>(O1, w2f, b2, feat);
  k_head<<<128, 256, 0, stream>>>(diffs, feat, gwT2, gb, w4, b4, w5, b5, out);
}

// Round 10
// 88.223 us; speedup vs baseline: 1.4265x; 1.0202x over previous
//
#include <hip/hip_runtime.h>
#include <hip/hip_bf16.h>

#define H1 57   // 64-8+1
#define H2 53   // 57-5+1
#define XP 60   // padded x-stride (x slots)

typedef _Float16 f16;
typedef _Float16 f16x4 __attribute__((ext_vector_type(4)));
typedef _Float16 f16x8 __attribute__((ext_vector_type(8)));
typedef float f32x4 __attribute__((ext_vector_type(4)));
typedef float f32x16 __attribute__((ext_vector_type(16)));

// ---------------- weight repack + gw transpose + feat zero (grid 32) ----------------
// w1f[(tp*64+l)*8+j] = W1[oc=l&15][c=j&3][kh=tp][kw=2*(l>>4)+(j>>2)]  (c==3 -> 0)
// w2f (32x32x16 fragments): w2f[(tap*64+l)*8+j] = W2[oc=l&31][ch=(l>>5)*8+j][tap]
// gwT2[c*256+t] = {gw[(2t)*66+c], gw[(2t+1)*66+c]}
__global__ __launch_bounds__(256) void k_repack(const float* __restrict__ w1,
    const float* __restrict__ w2, const float* __restrict__ gw,
    f16* __restrict__ w1f, f16* __restrict__ w2f,
    float2* __restrict__ gwT2, float* __restrict__ feat)
{
  const int tid = blockIdx.x * 256 + threadIdx.x;
  const int stride = 32 * 256;
  for (int i = tid; i < 8 * 64 * 8; i += stride) {
    int j = i & 7;
    int l = (i >> 3) & 63;
    int tp = i >> 9;
    int c = j & 3;
    int kw = 2 * (l >> 4) + (j >> 2);
    int oc = l & 15;
    float v = (c < 3) ? w1[((oc * 3 + c) * 8 + tp) * 8 + kw] : 0.f;
    w1f[i] = (f16)v;
  }
  for (int i = tid; i < 25 * 64 * 8; i += stride) {
    int j = i & 7;
    int l = (i >> 3) & 63;
    int tap = i >> 9;
    int oc = l & 31;
    int ch = ((l >> 5) << 3) + j;
    w2f[i] = (f16)w2[((oc * 16 + ch) * 5 + tap / 5) * 5 + tap % 5];
  }
  for (int i = tid; i < 66 * 256; i += stride) {
    int t = i & 255;
    int c = i >> 8;
    float2 v;
    v.x = gw[(2 * t) * 66 + c];
    v.y = gw[(2 * t + 1) * 66 + c];
    gwT2[i] = v;
  }
  for (int i = tid; i < 512 * 32; i += stride) feat[i] = 0.f;   // atomicMax identity
}

// ---------------- conv1 via MFMA implicit GEMM -> O1[img][y][oct2][x60][c8] --------
__global__ __launch_bounds__(256) void k_conv1(const float* __restrict__ in,
    const f16* __restrict__ w1f, const float* __restrict__ b1,
    f16* __restrict__ O1)
{
  __shared__ __align__(16) f16 sIn[15][72][4];   // 8640 B, c4 channels-last
  __shared__ __align__(16) f16 sT[4][64][20];    // 10240 B, per-wave transpose
  const int img = blockIdx.x;
  const int y0 = min((int)blockIdx.y * 8, 49);
  const int lane = threadIdx.x & 63;
  const int wv = threadIdx.x >> 6;

  f16x8 Bf[8];
  #pragma unroll
  for (int tp = 0; tp < 8; ++tp)
    Bf[tp] = *(const f16x8*)&w1f[(tp * 64 + lane) * 8];

  for (int i = threadIdx.x; i < 15 * 16; i += 256) {
    int y = i >> 4, xq = i & 15;
    const float* p0 = &in[(((size_t)img * 3 + 0) * 64 + (y0 + y)) * 64 + xq * 4];
    float4 v0 = *(const float4*)p0;
    float4 v1 = *(const float4*)(p0 + 4096);
    float4 v2 = *(const float4*)(p0 + 8192);
    float c0[4] = {v0.x, v0.y, v0.z, v0.w};
    float c1[4] = {v1.x, v1.y, v1.z, v1.w};
    float c2[4] = {v2.x, v2.y, v2.z, v2.w};
    #pragma unroll
    for (int q = 0; q < 4; ++q) {
      f16x4 tt = {(f16)c0[q], (f16)c1[q], (f16)c2[q], (f16)0.f};
      *(f16x4*)&sIn[y][xq * 4 + q][0] = tt;
    }
  }
  for (int i = threadIdx.x; i < 15 * 8; i += 256) {
    int y = i >> 3, xi = i & 7;
    *(f16x4*)&sIn[y][64 + xi][0] = (f16x4){(f16)0.f, (f16)0.f, (f16)0.f, (f16)0.f};
  }
  __syncthreads();

  const int g = lane >> 4;
  const int n16 = lane & 15;

  const float bias = b1[n16];
  f32x4 acc[2][4];
  #pragma unroll
  for (int r = 0; r < 2; ++r)
    #pragma unroll
    for (int xt = 0; xt < 4; ++xt)
      acc[r][xt] = (f32x4){bias, bias, bias, bias};

  #pragma unroll
  for (int tp = 0; tp < 8; ++tp) {        // kh = tp
    #pragma unroll
    for (int r = 0; r < 2; ++r) {
      const int row = 2 * wv + r + tp;
      #pragma unroll
      for (int xt = 0; xt < 4; ++xt) {
        const int px = xt * 16 + n16;
        f16x4 a0 = *(const f16x4*)&sIn[row][px + 2 * g][0];
        f16x4 a1 = *(const f16x4*)&sIn[row][px + 2 * g + 1][0];
        union { struct { f16x4 lo, hi; } pr; f16x8 v; } u;
        u.pr.lo = a0; u.pr.hi = a1;
        acc[r][xt] = __builtin_amdgcn_mfma_f32_16x16x32_f16(u.v, Bf[tp], acc[r][xt], 0, 0, 0);
      }
    }
  }

  // epilogue: relu, per-wave LDS transpose (oc-major -> channels-last), then
  // two coalesced 16B stores per lane into the oct-split O1 layout
  #pragma unroll
  for (int r = 0; r < 2; ++r) {
    #pragma unroll
    for (int xt = 0; xt < 4; ++xt)
      #pragma unroll
      for (int q = 0; q < 4; ++q)
        sT[wv][xt * 16 + g * 4 + q][n16] = (f16)fmaxf(acc[r][xt][q], 0.f);
    const int yy = y0 + 2 * wv + r;
    if (lane < H1) {
      f16x4 v0 = *(const f16x4*)&sT[wv][lane][0];
      f16x4 v1 = *(const f16x4*)&sT[wv][lane][4];
      f16x4 v2 = *(const f16x4*)&sT[wv][lane][8];
      f16x4 v3 = *(const f16x4*)&sT[wv][lane][12];
      union { struct { f16x4 a, b; } pr; f16x8 v; } lo, hi;
      lo.pr.a = v0; lo.pr.b = v1;
      hi.pr.a = v2; hi.pr.b = v3;
      f16* dst = &O1[((((size_t)img * H1 + yy) * 2 + 0) * XP + lane) * 8];
      *(f16x8*)dst = lo.v;                 // oct 0: oc 0-7
      *(f16x8*)(dst + XP * 8) = hi.v;      // oct 1: oc 8-15
    }
  }
}

// ---------------- conv2: 32x32x16 MFMA, flattened-M (14 tiles), hybrid reg/LDS B ----
// grid (512, 7): y0 in {0,8,...,40,45}. block 256 = 4 waves (tiles 4/4/3/3).
// M flattened: p = y*53 + x in [0,424); tile t rows = t*32 + m32.
// sI[12y][2oct][60x][8c] filled by ONE linear copy (O1 layout matches).
__global__ __launch_bounds__(256, 4) void k_conv2(const f16* __restrict__ O1,
    const f16* __restrict__ w2f, const float* __restrict__ b2,
    float* __restrict__ feat)
{
  __shared__ __align__(16) f16 sW[17 * 64 * 8];            // 17408 B (taps 8..24)
  __shared__ __align__(16) f16 sI[12 * 2 * XP * 8 + 64];   // 23168 B
  __shared__ unsigned smax[32];
  const int img = blockIdx.x;
  const int y0 = min((int)blockIdx.y * 8, 45);
  const int lane = threadIdx.x & 63;
  const int wv = threadIdx.x >> 6;
  if (threadIdx.x < 32) smax[threadIdx.x] = 0u;

  // B-frags taps 0-7 from global (issued first; staging below hides latency)
  f16x8 Br[8];
  const f16* pBg = &w2f[lane * 8];
  #pragma unroll
  for (int t = 0; t < 8; ++t)
    Br[t] = *(const f16x8*)(pBg + t * 512);

  for (int i = threadIdx.x; i < 17 * 64; i += 256)
    ((float4*)sW)[i] = ((const float4*)w2f)[8 * 64 + i];
  // linear strip copy: 12 rows x 2 oct x 60 x x 8 c = 1440 float4
  {
    const float4* src = (const float4*)(O1 + (size_t)(img * H1 + y0) * (2 * XP * 8));
    for (int i = threadIdx.x; i < 1440; i += 256)
      ((float4*)sI)[i] = src[i];
  }
  __syncthreads();

  const int m32 = lane & 31;      // A row within tile / B,D col (oc)
  const int G = lane >> 5;        // channel octet

  // wave tile assignment: 4/4/3/3 over 14 tiles
  const int start = (wv < 2) ? wv * 4 : 8 + (wv - 2) * 3;
  const int cnt = (wv < 2) ? 4 : 3;

  const float bias = b2[m32];
  f32x16 acc[4];
  #pragma unroll
  for (int ti = 0; ti < 4; ++ti)
    #pragma unroll
    for (int q = 0; q < 16; ++q)
      acc[ti][q] = bias;

  // per-tile A base: p = t*32+m32 (clamped to 423), y=(p*1237)>>16, x=p-53y
  const f16* pA[4];
  #pragma unroll
  for (int ti = 0; ti < 4; ++ti) {
    int t = start + ti;
    int p = t * 32 + m32;
    p = min(p, 423);
    int y = (p * 1237) >> 16;
    int x = p - 53 * y;
    pA[ti] = &sI[((y * 2 + G) * XP + x) * 8];
  }

  #pragma unroll
  for (int tap = 0; tap < 25; ++tap) {
    const int kh = tap / 5, kw = tap % 5;
    const int off = (kh * 2 * XP + kw) * 8;    // const imm after unroll
    f16x8 Bv = (tap < 8) ? Br[tap] : *(const f16x8*)(&sW[lane * 8] + (tap - 8) * 512);
    #pragma unroll
    for (int ti = 0; ti < 4; ++ti) {
      if (ti < cnt) {
        f16x8 Av = *(const f16x8*)(pA[ti] + off);
        acc[ti] = __builtin_amdgcn_mfma_f32_32x32x16_f16(Av, Bv, acc[ti], 0, 0, 0);
      }
    }
  }

  // epilogue: relu + per-oc max. D row=(q&3)+8*(q>>2)+4*G (p_out = t*32+row);
  // only tile 13 rows >= 8 (q>=4) are clamped-garbage -> skip.
  float m = 0.f;
  #pragma unroll
  for (int ti = 0; ti < 4; ++ti) {
    if (ti < cnt) {
      const int t = start + ti;
      #pragma unroll
      for (int q = 0; q < 16; ++q) {
        if (t == 13 && q >= 4) continue;
        m = fmaxf(m, acc[ti][q]);
      }
    }
  }
  m = fmaxf(m, 0.f);   // relu
  m = fmaxf(m, __shfl_xor(m, 32, 64));
  if (lane < 32) atomicMax(&smax[m32], __float_as_uint(m));
  __syncthreads();
  if (threadIdx.x < 32)
    atomicMax((unsigned*)&feat[img * 32 + threadIdx.x], smax[threadIdx.x]);
}

// ---------------- head: adjacency + graph layer + MLP (coalesced GEMV) ----------------
__global__ __launch_bounds__(256) void k_head(const float* __restrict__ diffs,
    const float* __restrict__ feat, const float2* __restrict__ gwT2,
    const float* __restrict__ gb, const float* __restrict__ w4,
    const float* __restrict__ b4, const float* __restrict__ w5,
    const float* __restrict__ b5, float* __restrict__ out)
{
  __shared__ float h66[4][66];
  __shared__ float hout[4][512];
  __shared__ float Am[4][4];
  __shared__ float pd[4][4][2];
  __shared__ float fs[4][32];
  const int b = blockIdx.x;
  const int tid = threadIdx.x;
  if (tid < 128) {
    int i = tid >> 5, c = tid & 31;
    fs[i][c] = feat[(b * 4 + i) * 32 + c];
  }
  if (tid == 0) {
    float lx[4], ly[4];
    #pragma unroll
    for (int a = 0; a < 4; ++a) {
      lx[a] = diffs[(b * 4 + a) * 2];
      ly[a] = diffs[(b * 4 + a) * 2 + 1];
    }
    #pragma unroll
    for (int i = 0; i < 4; ++i) {
      float A[4];
      float rs = 0.f;
      #pragma unroll
      for (int j = 0; j < 4; ++j) {
        float dx = lx[i] - lx[j], dy = ly[i] - ly[j];
        pd[i][j][0] = dx;
        pd[i][j][1] = dy;
        float n = sqrtf(dx * dx + dy * dy);
        A[j] = (n < 1.41421356237309504880f) ? 1.f : 0.f;
        rs += A[j];
      }
      float inv = 1.f / fmaxf(rs, 1e-6f);
      #pragma unroll
      for (int j = 0; j < 4; ++j)
        Am[i][j] = (i == j) ? 0.f : A[j] * inv;
    }
  }
  __syncthreads();
  if (tid < 128) {
    int i = tid >> 5, c = tid & 31;
    h66[i][c] = fs[i][c];
    float s = 0.f;
    #pragma unroll
    for (int j = 0; j < 4; ++j) s += Am[i][j] * fs[j][c];
    h66[i][32 + c] = s;
  } else if (tid < 136) {
    int q = tid - 128;
    int i = q >> 1, d = q & 1;
    float s = 0.f;
    #pragma unroll
    for (int j = 0; j < 4; ++j) s += Am[i][j] * pd[i][j][d];
    h66[i][64 + d] = s;
  }
  __syncthreads();
  {
    const float b0 = gb[2 * tid], b1g = gb[2 * tid + 1];
    float a[4][2];
    #pragma unroll
    for (int i = 0; i < 4; ++i) { a[i][0] = b0; a[i][1] = b1g; }
    #pragma unroll 6
    for (int c = 0; c < 66; ++c) {
      float2 w = gwT2[c * 256 + tid];
      #pragma unroll
      for (int i = 0; i < 4; ++i) {
        float h = h66[i][c];
        a[i][0] = fmaf(h, w.x, a[i][0]);
        a[i][1] = fmaf(h, w.y, a[i][1]);
      }
    }
    #pragma unroll
    for (int i = 0; i < 4; ++i) {
      float2 v;
      v.x = fmaxf(a[i][0], 0.f);
      v.y = fmaxf(a[i][1], 0.f);
      *(float2*)&hout[i][2 * tid] = v;
    }
  }
  __syncthreads();
  if (tid < 192) {
    int gq = tid >> 4, l = tid & 15;
    int i = gq / 3, k = gq % 3;
    const float* wrow = (k < 2) ? &w4[k * 512] : w5;
    float s = 0.f;
    for (int o = l; o < 512; o += 16) s = fmaf(hout[i][o], wrow[o], s);
    #pragma unroll
    for (int d = 8; d >= 1; d >>= 1) s += __shfl_xor(s, d, 16);
    if (l == 0) {
      if (k < 2) out[(b * 4 + i) * 2 + k] = s + b4[k];
      else       out[1024 + b * 4 + i] = s + b5[0];
    }
  }
}

extern "C" void kernel_launch(void* const* d_in, const int* in_sizes, int n_in,
                              void* d_out, int out_size, void* d_ws, size_t ws_size,
                              hipStream_t stream) {
  const float* diffs  = (const float*)d_in[0];
  const float* states = (const float*)d_in[1];
  const float* w1 = (const float*)d_in[2];
  const float* b1 = (const float*)d_in[3];
  const float* w2 = (const float*)d_in[4];
  const float* b2 = (const float*)d_in[5];
  const float* gw = (const float*)d_in[6];
  const float* gb = (const float*)d_in[7];
  const float* w4 = (const float*)d_in[8];
  const float* b4 = (const float*)d_in[9];
  const float* w5 = (const float*)d_in[10];
  const float* b5 = (const float*)d_in[11];
  float* out = (float*)d_out;

  char* base = (char*)d_ws;
  f16*    w1f  = (f16*)base;                    // 8192 B
  f16*    w2f  = (f16*)(base + 8192);           // 25600 B -> ends 33792
  float2* gwT2 = (float2*)(base + 34816);       // 135168 B -> 169984
  float*  feat = (float*)(base + 169984);       // 65536 B -> 235520
  f16*    O1   = (f16*)(base + 235520);         // 512*57*2*60*8 f16 = 56.0 MB

  k_repack<<<32, 256, 0, stream>>>(w1, w2, gw, w1f, w2f, gwT2, feat);
  k_conv1<<<dim3(512, 8), 256, 0, stream>>>(states, w1f, b1, O1);
  k_conv2<<<dim3(512, 7), 256, 0, stream>>>(O1, w2f, b2, feat);
  k_head<<<128, 256, 0, stream>>>(diffs, feat, gwT2, gb, w4, b4, w5, b5, out);
}

// Round 11
// 86.840 us; speedup vs baseline: 1.4492x; 1.0159x over previous
//
#include <hip/hip_runtime.h>
#include <hip/hip_bf16.h>

#define H1 57   // 64-8+1
#define H2 53   // 57-5+1
#define XP 60   // padded x-stride (x slots)
#define SIP 968 // padded sI y-row stride in f16 (2*60*8 + 8 -> 4-bank rotation)

typedef _Float16 f16;
typedef _Float16 f16x4 __attribute__((ext_vector_type(4)));
typedef _Float16 f16x8 __attribute__((ext_vector_type(8)));
typedef float f32x4 __attribute__((ext_vector_type(4)));
typedef float f32x16 __attribute__((ext_vector_type(16)));

// ---------------- weight repack + gw transpose + feat zero (grid 32) ----------------
// w1f[(tp*64+l)*8+j] = W1[oc=l&15][c=j&3][kh=tp][kw=2*(l>>4)+(j>>2)]  (c==3 -> 0)
// w2f (32x32x16 fragments): w2f[(tap*64+l)*8+j] = W2[oc=l&31][ch=(l>>5)*8+j][tap]
// gwT2[c*256+t] = {gw[(2t)*66+c], gw[(2t+1)*66+c]}
__global__ __launch_bounds__(256) void k_repack(const float* __restrict__ w1,
    const float* __restrict__ w2, const float* __restrict__ gw,
    f16* __restrict__ w1f, f16* __restrict__ w2f,
    float2* __restrict__ gwT2, float* __restrict__ feat)
{
  const int tid = blockIdx.x * 256 + threadIdx.x;
  const int stride = 32 * 256;
  for (int i = tid; i < 8 * 64 * 8; i += stride) {
    int j = i & 7;
    int l = (i >> 3) & 63;
    int tp = i >> 9;
    int c = j & 3;
    int kw = 2 * (l >> 4) + (j >> 2);
    int oc = l & 15;
    float v = (c < 3) ? w1[((oc * 3 + c) * 8 + tp) * 8 + kw] : 0.f;
    w1f[i] = (f16)v;
  }
  for (int i = tid; i < 25 * 64 * 8; i += stride) {
    int j = i & 7;
    int l = (i >> 3) & 63;
    int tap = i >> 9;
    int oc = l & 31;
    int ch = ((l >> 5) << 3) + j;
    w2f[i] = (f16)w2[((oc * 16 + ch) * 5 + tap / 5) * 5 + tap % 5];
  }
  for (int i = tid; i < 66 * 256; i += stride) {
    int t = i & 255;
    int c = i >> 8;
    float2 v;
    v.x = gw[(2 * t) * 66 + c];
    v.y = gw[(2 * t + 1) * 66 + c];
    gwT2[i] = v;
  }
  for (int i = tid; i < 512 * 32; i += stride) feat[i] = 0.f;   // atomicMax identity
}

// ---------------- conv1: MFMA implicit GEMM, SWAPPED operands -> direct store ------
// mfma(W_frag, X_frag): D[oc][px] -> lane holds 4 consecutive oc (g*4+q) at px=n16.
// Store 8B f16x4 straight into O1[img][y][oct2][x60][c8]; no LDS transpose.
__global__ __launch_bounds__(256) void k_conv1(const float* __restrict__ in,
    const f16* __restrict__ w1f, const float* __restrict__ b1,
    f16* __restrict__ O1)
{
  __shared__ __align__(16) f16 sIn[15][72][4];   // 8640 B, c4 channels-last
  const int img = blockIdx.x;
  const int y0 = min((int)blockIdx.y * 8, 49);
  const int lane = threadIdx.x & 63;
  const int wv = threadIdx.x >> 6;

  f16x8 Bf[8];
  #pragma unroll
  for (int tp = 0; tp < 8; ++tp)
    Bf[tp] = *(const f16x8*)&w1f[(tp * 64 + lane) * 8];

  for (int i = threadIdx.x; i < 15 * 16; i += 256) {
    int y = i >> 4, xq = i & 15;
    const float* p0 = &in[(((size_t)img * 3 + 0) * 64 + (y0 + y)) * 64 + xq * 4];
    float4 v0 = *(const float4*)p0;
    float4 v1 = *(const float4*)(p0 + 4096);
    float4 v2 = *(const float4*)(p0 + 8192);
    float c0[4] = {v0.x, v0.y, v0.z, v0.w};
    float c1[4] = {v1.x, v1.y, v1.z, v1.w};
    float c2[4] = {v2.x, v2.y, v2.z, v2.w};
    #pragma unroll
    for (int q = 0; q < 4; ++q) {
      f16x4 tt = {(f16)c0[q], (f16)c1[q], (f16)c2[q], (f16)0.f};
      *(f16x4*)&sIn[y][xq * 4 + q][0] = tt;
    }
  }
  for (int i = threadIdx.x; i < 15 * 8; i += 256) {
    int y = i >> 3, xi = i & 7;
    *(f16x4*)&sIn[y][64 + xi][0] = (f16x4){(f16)0.f, (f16)0.f, (f16)0.f, (f16)0.f};
  }
  __syncthreads();

  const int g = lane >> 4;       // selects 4-oc group (D rows) + A k-part
  const int n16 = lane & 15;     // px within tile (D col)

  const f32x4 biasv = {b1[g * 4 + 0], b1[g * 4 + 1], b1[g * 4 + 2], b1[g * 4 + 3]};
  f32x4 acc[2][4];
  #pragma unroll
  for (int r = 0; r < 2; ++r)
    #pragma unroll
    for (int xt = 0; xt < 4; ++xt)
      acc[r][xt] = biasv;

  #pragma unroll
  for (int tp = 0; tp < 8; ++tp) {        // kh = tp
    #pragma unroll
    for (int r = 0; r < 2; ++r) {
      const int row = 2 * wv + r + tp;
      #pragma unroll
      for (int xt = 0; xt < 4; ++xt) {
        const int px = xt * 16 + n16;
        f16x4 a0 = *(const f16x4*)&sIn[row][px + 2 * g][0];
        f16x4 a1 = *(const f16x4*)&sIn[row][px + 2 * g + 1][0];
        union { struct { f16x4 lo, hi; } pr; f16x8 v; } u;
        u.pr.lo = a0; u.pr.hi = a1;
        // swapped operands: weights first -> D[oc][px]
        acc[r][xt] = __builtin_amdgcn_mfma_f32_16x16x32_f16(Bf[tp], u.v, acc[r][xt], 0, 0, 0);
      }
    }
  }

  // epilogue: relu + direct 8B store (4 oc at px) into oct-split channels-last O1
  #pragma unroll
  for (int r = 0; r < 2; ++r) {
    const int yy = y0 + 2 * wv + r;
    f16* rowp = &O1[(((size_t)img * H1 + yy) * 2 + (g >> 1)) * XP * 8 + (g & 1) * 4];
    #pragma unroll
    for (int xt = 0; xt < 4; ++xt) {
      const int px = xt * 16 + n16;
      if (px < H1) {
        f16x4 v;
        #pragma unroll
        for (int q = 0; q < 4; ++q) v[q] = (f16)fmaxf(acc[r][xt][q], 0.f);
        *(f16x4*)&rowp[px * 8] = v;
      }
    }
  }
}

// ---------------- conv2: 32x32x16 MFMA, flattened-M, padded sI, 9-reg-tap hybrid ----
// grid (512, 7): y0 in {0,8,...,40,45}. block 256 = 4 waves (tiles 4/4/3/3).
// sI y-row stride = SIP=968 f16 (16B pad -> 4-bank rotation, kills wrap conflicts).
__global__ __launch_bounds__(256, 4) void k_conv2(const f16* __restrict__ O1,
    const f16* __restrict__ w2f, const float* __restrict__ b2,
    float* __restrict__ feat)
{
  __shared__ __align__(16) f16 sW[16 * 64 * 8];            // 16384 B (taps 9..24)
  __shared__ __align__(16) f16 sI[12 * SIP + 16];          // 23296 B
  __shared__ unsigned smax[32];
  const int img = blockIdx.x;
  const int y0 = min((int)blockIdx.y * 8, 45);
  const int lane = threadIdx.x & 63;
  const int wv = threadIdx.x >> 6;
  if (threadIdx.x < 32) smax[threadIdx.x] = 0u;

  // B-frags taps 0-8 from global (issued first; staging below hides latency)
  f16x8 Br[9];
  const f16* pBg = &w2f[lane * 8];
  #pragma unroll
  for (int t = 0; t < 9; ++t)
    Br[t] = *(const f16x8*)(pBg + t * 512);

  for (int i = threadIdx.x; i < 16 * 64; i += 256)
    ((float4*)sW)[i] = ((const float4*)w2f)[9 * 64 + i];
  // strip copy with per-y pad: 12 rows x 120 float4
  {
    const float4* src = (const float4*)(O1 + (size_t)(img * H1 + y0) * (2 * XP * 8));
    for (int i = threadIdx.x; i < 1440; i += 256) {
      int y = i / 120;
      int rem = i - y * 120;
      ((float4*)&sI[y * SIP])[rem] = src[i];
    }
  }
  __syncthreads();

  const int m32 = lane & 31;      // A row within tile / B,D col (oc)
  const int G = lane >> 5;        // channel octet

  // wave tile assignment: 4/4/3/3 over 14 tiles
  const int start = (wv < 2) ? wv * 4 : 8 + (wv - 2) * 3;
  const int cnt = (wv < 2) ? 4 : 3;

  const float bias = b2[m32];
  f32x16 acc[4];
  #pragma unroll
  for (int ti = 0; ti < 4; ++ti)
    #pragma unroll
    for (int q = 0; q < 16; ++q)
      acc[ti][q] = bias;

  // per-tile A base: p = t*32+m32 (clamped to 423), y=(p*1237)>>16, x=p-53y
  const f16* pA[4];
  #pragma unroll
  for (int ti = 0; ti < 4; ++ti) {
    int t = start + ti;
    int p = t * 32 + m32;
    p = min(p, 423);
    int y = (p * 1237) >> 16;
    int x = p - 53 * y;
    pA[ti] = &sI[y * SIP + G * 480 + x * 8];
  }

  #pragma unroll
  for (int tap = 0; tap < 25; ++tap) {
    const int kh = tap / 5, kw = tap % 5;
    const int off = kh * SIP + kw * 8;         // const imm after unroll
    f16x8 Bv = (tap < 9) ? Br[tap] : *(const f16x8*)(&sW[lane * 8] + (tap - 9) * 512);
    #pragma unroll
    for (int ti = 0; ti < 4; ++ti) {
      if (ti < cnt) {
        f16x8 Av = *(const f16x8*)(pA[ti] + off);
        acc[ti] = __builtin_amdgcn_mfma_f32_32x32x16_f16(Av, Bv, acc[ti], 0, 0, 0);
      }
    }
  }

  // epilogue: relu + per-oc max. D row=(q&3)+8*(q>>2)+4*G (p_out = t*32+row);
  // only tile 13 rows >= 8 (q>=4) are clamped-garbage -> skip.
  float m = 0.f;
  #pragma unroll
  for (int ti = 0; ti < 4; ++ti) {
    if (ti < cnt) {
      const int t = start + ti;
      #pragma unroll
      for (int q = 0; q < 16; ++q) {
        if (t == 13 && q >= 4) continue;
        m = fmaxf(m, acc[ti][q]);
      }
    }
  }
  m = fmaxf(m, 0.f);   // relu
  m = fmaxf(m, __shfl_xor(m, 32, 64));
  if (lane < 32) atomicMax(&smax[m32], __float_as_uint(m));
  __syncthreads();
  if (threadIdx.x < 32)
    atomicMax((unsigned*)&feat[img * 32 + threadIdx.x], smax[threadIdx.x]);
}

// ---------------- head: adjacency + graph layer + MLP (coalesced GEMV) ----------------
__global__ __launch_bounds__(256) void k_head(const float* __restrict__ diffs,
    const float* __restrict__ feat, const float2* __restrict__ gwT2,
    const float* __restrict__ gb, const float* __restrict__ w4,
    const float* __restrict__ b4, const float* __restrict__ w5,
    const float* __restrict__ b5, float* __restrict__ out)
{
  __shared__ float h66[4][66];
  __shared__ float hout[4][512];
  __shared__ float Am[4][4];
  __shared__ float pd[4][4][2];
  __shared__ float fs[4][32];
  const int b = blockIdx.x;
  const int tid = threadIdx.x;
  if (tid < 128) {
    int i = tid >> 5, c = tid & 31;
    fs[i][c] = feat[(b * 4 + i) * 32 + c];
  }
  if (tid == 0) {
    float lx[4], ly[4];
    #pragma unroll
    for (int a = 0; a < 4; ++a) {
      lx[a] = diffs[(b * 4 + a) * 2];
      ly[a] = diffs[(b * 4 + a) * 2 + 1];
    }
    #pragma unroll
    for (int i = 0; i < 4; ++i) {
      float A[4];
      float rs = 0.f;
      #pragma unroll
      for (int j = 0; j < 4; ++j) {
        float dx = lx[i] - lx[j], dy = ly[i] - ly[j];
        pd[i][j][0] = dx;
        pd[i][j][1] = dy;
        float n = sqrtf(dx * dx + dy * dy);
        A[j] = (n < 1.41421356237309504880f) ? 1.f : 0.f;
        rs += A[j];
      }
      float inv = 1.f / fmaxf(rs, 1e-6f);
      #pragma unroll
      for (int j = 0; j < 4; ++j)
        Am[i][j] = (i == j) ? 0.f : A[j] * inv;
    }
  }
  __syncthreads();
  if (tid < 128) {
    int i = tid >> 5, c = tid & 31;
    h66[i][c] = fs[i][c];
    float s = 0.f;
    #pragma unroll
    for (int j = 0; j < 4; ++j) s += Am[i][j] * fs[j][c];
    h66[i][32 + c] = s;
  } else if (tid < 136) {
    int q = tid - 128;
    int i = q >> 1, d = q & 1;
    float s = 0.f;
    #pragma unroll
    for (int j = 0; j < 4; ++j) s += Am[i][j] * pd[i][j][d];
    h66[i][64 + d] = s;
  }
  __syncthreads();
  {
    const float b0 = gb[2 * tid], b1g = gb[2 * tid + 1];
    float a[4][2];
    #pragma unroll
    for (int i = 0; i < 4; ++i) { a[i][0] = b0; a[i][1] = b1g; }
    #pragma unroll 6
    for (int c = 0; c < 66; ++c) {
      float2 w = gwT2[c * 256 + tid];
      #pragma unroll
      for (int i = 0; i < 4; ++i) {
        float h = h66[i][c];
        a[i][0] = fmaf(h, w.x, a[i][0]);
        a[i][1] = fmaf(h, w.y, a[i][1]);
      }
    }
    #pragma unroll
    for (int i = 0; i < 4; ++i) {
      float2 v;
      v.x = fmaxf(a[i][0], 0.f);
      v.y = fmaxf(a[i][1], 0.f);
      *(float2*)&hout[i][2 * tid] = v;
    }
  }
  __syncthreads();
  if (tid < 192) {
    int gq = tid >> 4, l = tid & 15;
    int i = gq / 3, k = gq % 3;
    const float* wrow = (k < 2) ? &w4[k * 512] : w5;
    float s = 0.f;
    for (int o = l; o < 512; o += 16) s = fmaf(hout[i][o], wrow[o], s);
    #pragma unroll
    for (int d = 8; d >= 1; d >>= 1) s += __shfl_xor(s, d, 16);
    if (l == 0) {
      if (k < 2) out[(b * 4 + i) * 2 + k] = s + b4[k];
      else       out[1024 + b * 4 + i] = s + b5[0];
    }
  }
}

extern "C" void kernel_launch(void* const* d_in, const int* in_sizes, int n_in,
                              void* d_out, int out_size, void* d_ws, size_t ws_size,
                              hipStream_t stream) {
  const float* diffs  = (const float*)d_in[0];
  const float* states = (const float*)d_in[1];
  const float* w1 = (const float*)d_in[2];
  const float* b1 = (const float*)d_in[3];
  const float* w2 = (const float*)d_in[4];
  const float* b2 = (const float*)d_in[5];
  const float* gw = (const float*)d_in[6];
  const float* gb = (const float*)d_in[7];
  const float* w4 = (const float*)d_in[8];
  const float* b4 = (const float*)d_in[9];
  const float* w5 = (const float*)d_in[10];
  const float* b5 = (const float*)d_in[11];
  float* out = (float*)d_out;

  char* base = (char*)d_ws;
  f16*    w1f  = (f16*)base;                    // 8192 B
  f16*    w2f  = (f16*)(base + 8192);           // 25600 B -> ends 33792
  float2* gwT2 = (float2*)(base + 34816);       // 135168 B -> 169984
  float*  feat = (float*)(base + 169984);       // 65536 B -> 235520
  f16*    O1   = (f16*)(base + 235520);         // 512*57*2*60*8 f16 = 56.0 MB

  k_repack<<<32, 256, 0, stream>>>(w1, w2, gw, w1f, w2f, gwT2, feat);
  k_conv1<<<dim3(512, 8), 256, 0, stream>>>(states, w1f, b1, O1);
  k_conv2<<<dim3(512, 7), 256, 0, stream>>>(O1, w2f, b2, feat);
  k_head<<<128, 256, 0, stream>>>(diffs, feat, gwT2, gb, w4, b4, w5, b5, out);
}